// Round 11
// baseline (765.262 us; speedup 1.0000x reference)
//
#include <hip/hip_runtime.h>

// GTA model: GCN(2-hop) -> 3x transformer encoder -> 10-step AR predictor.
// R10: attention goes to 256 queries/block (4 subtiles share each staged
// xr/xt tile) -> LDS reads, DMA, and barriers per query halve. P-scratch
// unpadded + XOR-chunk swizzled to fit 64KB LDS. launch_bounds(256,2).
// Tail fused per layer (R9); attention staging pattern from R7.

#define ROWS 24576   // C*T = 32*768

// workspace offsets (floats)
#define OFF_ADJ   0L
#define OFF_X0    1024L
#define OFF_X1    (OFF_X0 + 2457600L)
#define OFF_HID   (OFF_X1 + 2457600L)
#define OFF_XROW  (OFF_HID + 1474560L)       // 24576*128 bf16 = 1572864 floats
#define OFF_XT    (OFF_XROW + 1572864L)
#define OFF_WBF   (OFF_XT + 1572864L)        // 24576*512 bf16 = 6291456 floats
#define OFF_MHT   (OFF_WBF + 6291456L)       // 15*128*128 bf16 = 122880 floats
#define OFF_USTT  (OFF_MHT + 122880L)        // 3*128*512 bf16 = 98304 floats
#define OFF_MP    (OFF_USTT + 98304L)        // 100*100 fp32
#define OFF_C0    (OFF_MP + 10000L)          // 100 fp32 (pad to 128)
#define OFF_F1WT  (OFF_C0 + 128L)            // 3*64*128 bf16 = 12288 floats
#define OFF_F2WT  (OFF_F1WT + 12288L)        // 3*112*64 bf16 = 10752 floats

typedef __attribute__((ext_vector_type(8))) short short8;
typedef __attribute__((ext_vector_type(4))) float float4v;
typedef __attribute__((ext_vector_type(2))) unsigned int uint2v;

__device__ inline unsigned short f2bf(float f) {
    unsigned u = __builtin_bit_cast(unsigned, f);
    return (unsigned short)((u + 0x7fffu + ((u >> 16) & 1u)) >> 16);
}
__device__ inline unsigned pk2bf(float lo, float hi) {
    return (unsigned)f2bf(lo) | ((unsigned)f2bf(hi) << 16);
}
// async global->LDS DMA, 16B per lane; LDS dest = wave-uniform base + lane*16
__device__ inline void gload16(const short* g, short* l) {
    __builtin_amdgcn_global_load_lds((const __attribute__((address_space(1))) void*)g,
                                     (__attribute__((address_space(3))) void*)l, 16, 0, 0);
}

// ---------------- adjacency normalization ----------------
__global__ void __launch_bounds__(1024) k_adj(const float* __restrict__ A, float* __restrict__ adjh) {
    __shared__ float adj[32][32];
    __shared__ float rs[32];
    int tid = threadIdx.x;
    int i = tid >> 5, j = tid & 31;
    float v = A[i*32 + j] + (i == j ? 1.f : 0.f);
    adj[i][j] = v;
    __syncthreads();
    if (tid < 32) {
        float s = 0.f;
        #pragma unroll
        for (int jj = 0; jj < 32; ++jj) s += adj[tid][jj];
        rs[tid] = s;
    }
    __syncthreads();
    adjh[i*32 + j] = adj[i][j] / rs[i];
}

// ---------------- precompute (parallel): MhT, UstT, f1wT, f2wT (bf16 padded), Mpred, c0 ----
__global__ void __launch_bounds__(256) k_mu2(const float* __restrict__ wq, const float* __restrict__ wk,
                                             const float* __restrict__ wv, const float* __restrict__ wm,
                                             const float* __restrict__ l1w, const float* __restrict__ l1b,
                                             const float* __restrict__ l2w, const float* __restrict__ l2b,
                                             const float* __restrict__ f1w, const float* __restrict__ f2w,
                                             unsigned short* __restrict__ MhT, unsigned short* __restrict__ UstT,
                                             float* __restrict__ Mp, float* __restrict__ c0v,
                                             unsigned short* __restrict__ f1wT, unsigned short* __restrict__ f2wT) {
    int bi = blockIdx.x, tid = threadIdx.x;
    if (bi < 480) {
        int mat = bi >> 4, sub = bi & 15;
        int mode = mat / 15, idx = mat % 15, l = idx / 5, h = idx % 5;
        const float* Asrc = (mode == 0 ? wq : wv) + (l*5 + h)*10000;
        const float* Bsrc = (mode == 0) ? (wk + (l*5 + h)*10000) : (wm + l*50000 + h*10000);
        int oend = sub*625 + 625;
        for (int o = sub*625 + tid; o < oend; o += 256) {
            int r = o / 100, cix = o - (o/100)*100;
            const float* arow = Asrc + r*100;
            float acc = 0.f;
            if (mode == 0) {
                const float* brow = Bsrc + cix*100;
                for (int e = 0; e < 100; ++e) acc += arow[e] * brow[e];
                MhT[(long)(l*5 + h)*16384 + cix*128 + r] = f2bf(acc * 0.1f);
            } else {
                for (int e = 0; e < 100; ++e) acc += arow[e] * Bsrc[e*100 + cix];
                UstT[(long)l*65536 + (long)cix*512 + h*100 + r] = f2bf(acc);
            }
        }
        if (sub == 0) {   // zero padding
            if (mode == 0) {
                unsigned short* M0 = MhT + (long)(l*5 + h)*16384;
                for (int i = tid; i < 28*128; i += 256) M0[(100 + i/128)*128 + (i%128)] = 0;
                for (int i = tid; i < 100*28; i += 256) M0[(i/28)*128 + 100 + (i%28)] = 0;
            } else if (h == 4) {
                unsigned short* U0 = UstT + (long)l*65536;
                for (int i = tid; i < 28*512; i += 256) U0[(long)(100 + i/512)*512 + (i%512)] = 0;
                for (int i = tid; i < 100*12; i += 256) U0[(long)(i/12)*512 + 500 + (i%12)] = 0;
            }
        }
    } else if (bi < 496) {
        int sub = bi - 480;
        int oend = sub*625 + 625;
        for (int o = sub*625 + tid; o < oend; o += 256) {
            int r = o / 100, cix = o - (o/100)*100;
            const float* arow = l1w + r*200;
            float acc = 0.f;
            for (int e = 0; e < 200; ++e) acc += arow[e] * l2w[e*100 + cix];
            Mp[r*100 + cix] = acc;
        }
    } else if (bi == 496) {
        if (tid < 100) {
            float acc = l2b[tid];
            for (int e = 0; e < 200; ++e) acc += l1b[e] * l2w[e*100 + tid];
            c0v[tid] = acc;
        }
    } else {
        int l = bi - 497;   // per-layer FFN weight transposes
        unsigned short* F1 = f1wT + (long)l*8192;
        for (int i = tid; i < 8192; i += 256) {
            int o = i >> 7, k = i & 127;
            F1[i] = (k < 100) ? f2bf(f1w[l*6400 + k*64 + o]) : (unsigned short)0;
        }
        unsigned short* F2 = f2wT + (long)l*7168;
        for (int i = tid; i < 7168; i += 256) {
            int o2 = i >> 6, k2 = i & 63;
            F2[i] = (o2 < 100) ? f2bf(f2w[l*6400 + k2*100 + o2]) : (unsigned short)0;
        }
    }
}

// ---------------- spmm: Y[i,f] = sum_j adjh[i,j] * Xin[j,f] ----------------
__global__ void __launch_bounds__(256) k_spmm(const float* __restrict__ adjh, const float* __restrict__ Xin,
                                              float* __restrict__ Y, int F) {
    __shared__ float adj[1024];
    int tid = threadIdx.x;
    for (int i = tid; i < 1024; i += 256) adj[i] = adjh[i];
    __syncthreads();
    long f = (long)blockIdx.x * 256 + tid;
    float acc[32];
    #pragma unroll
    for (int i = 0; i < 32; ++i) acc[i] = 0.f;
    for (int jj = 0; jj < 32; ++jj) {
        float xv = Xin[jj*(long)F + f];
        #pragma unroll
        for (int i = 0; i < 32; ++i) acc[i] += adj[i*32 + jj] * xv;
    }
    #pragma unroll
    for (int i = 0; i < 32; ++i) Y[i*(long)F + f] = acc[i];
}

// ---------------- fp32 tiled GEMM (GCN only) ----------------
template<int NCOLS, bool RELU, bool BIAS>
__global__ void __launch_bounds__(256) k_gemm(const float* __restrict__ A, const float* __restrict__ B,
                                              const float* __restrict__ bias, float* __restrict__ Cc,
                                              int M, int N, int K) {
    constexpr int NP = 8*NCOLS;
    int tid = threadIdx.x;
    int m0 = blockIdx.x * 32;
    int mloc = tid & 31, grp = tid >> 5;
    int n0 = grp * NCOLS;
    __shared__ float As[32][33];
    __shared__ float Bs[32][NP + 1];
    float acc[NCOLS];
    #pragma unroll
    for (int i2 = 0; i2 < NCOLS; ++i2) acc[i2] = 0.f;
    for (int k0 = 0; k0 < K; k0 += 32) {
        #pragma unroll
        for (int st = 0; st < 4; ++st) {
            int rr = (tid >> 5) + st*8, kk = tid & 31, gk = k0 + kk;
            As[rr][kk] = (gk < K) ? A[(long)(m0 + rr)*K + gk] : 0.f;
        }
        for (int i2 = tid; i2 < 32*NP; i2 += 256) {
            int kk = i2 / NP, nn = i2 - kk*NP;
            int gk = k0 + kk;
            Bs[kk][nn] = (gk < K && nn < N) ? B[(long)gk*N + nn] : 0.f;
        }
        __syncthreads();
        #pragma unroll 8
        for (int kk = 0; kk < 32; ++kk) {
            float a = As[mloc][kk];
            #pragma unroll
            for (int j2 = 0; j2 < NCOLS; ++j2) acc[j2] += a * Bs[kk][n0 + j2];
        }
        __syncthreads();
    }
    #pragma unroll
    for (int j2 = 0; j2 < NCOLS; ++j2) {
        int nn = n0 + j2;
        if (nn < N) {
            float v = acc[j2];
            if (BIAS) v += bias[nn];
            if (RELU) v = fmaxf(v, 0.f);
            Cc[(long)(m0 + mloc)*N + nn] = v;
        }
    }
}

// ---------------- x fp32 -> bf16 row-major [c][t][128] and transposed [c][128][t] ----------------
__global__ void __launch_bounds__(256) k_prep(const float* __restrict__ x, unsigned short* __restrict__ xrow,
                                              unsigned short* __restrict__ xT) {
    int c = blockIdx.y, t0 = blockIdx.x * 64;
    int tid = threadIdx.x;
    __shared__ float xs[64][101];
    const float* xp = x + ((long)c*768 + t0) * 100;
    for (int i = tid; i < 6400; i += 256) {
        int r = i / 100, d = i - r*100;
        xs[r][d] = xp[i];
    }
    __syncthreads();
    unsigned short* xro = xrow + ((long)c*768 + t0) * 128;
    for (int i = tid; i < 8192; i += 256) {
        int r = i >> 7, d = i & 127;
        xro[i] = (d < 100) ? f2bf(xs[r][d]) : (unsigned short)0;
    }
    unsigned short* xto = xT + (long)c*128*768 + t0;
    for (int i = tid; i < 8192; i += 256) {
        int d = i >> 6, t = i & 63;
        xto[(long)d*768 + t] = (d < 100) ? f2bf(xs[t][d]) : (unsigned short)0;
    }
}

// ---------------- fused Q-proj + flash attention, 256 queries/block ----------------
// grid (3, 5, 32) = (256-query tile, h, c); block 256 = 4 waves x 16 q x 4 subtiles.
// xr/xt DMA-staged with XOR-swizzled chunks (R7); P scratch stride 64, XOR swizzle.
#define QP_STRIDE 136

__global__ void __launch_bounds__(256, 2) k_attn7(const unsigned short* __restrict__ xrow,
                                                  const unsigned short* __restrict__ xT,
                                                  const unsigned short* __restrict__ MhT,
                                                  unsigned short* __restrict__ Wb) {
    __shared__ __align__(16) short xr[64 * 128];            // 16384 B
    __shared__ __align__(16) short xt[112 * 64];            // 14336 B
    __shared__ __align__(16) short scratch[4][4096];        // 32768 B: Q-xpose / pt[4]
    const int tid = threadIdx.x;
    const int wave = tid >> 6, lane = tid & 63;
    const int l15 = lane & 15, l4 = lane >> 4;
    const int c = blockIdx.z, h = blockIdx.y, q0 = blockIdx.x * 256;
    const int sw = l15 & 7;
    short* myq = scratch[wave];

    // ---- Q^T projection for 4 subtiles (sequential; wave-private transpose) ----
    short8 qb[4][4];   // [sub][ks]
    {
        const short* xq = (const short*)xrow + ((long)c*768 + q0 + wave*16 + l15)*128 + l4*8;
        const short* Mb = (const short*)MhT + (long)h*16384 + l15*128 + l4*8;
        for (int sub = 0; sub < 4; ++sub) {
            short8 bq[4];
            #pragma unroll
            for (int kk = 0; kk < 4; ++kk) bq[kk] = *(const short8*)(xq + sub*64*128 + kk*32);
            float4v qc[8];
            #pragma unroll
            for (int mt = 0; mt < 8; ++mt) qc[mt] = (float4v){0,0,0,0};
            #pragma unroll
            for (int mt = 0; mt < 8; ++mt) {
                #pragma unroll
                for (int kk = 0; kk < 4; ++kk) {
                    short8 a = *(const short8*)(Mb + (mt*16)*128 + kk*32);
                    qc[mt] = __builtin_amdgcn_mfma_f32_16x16x32_bf16(a, bq[kk], qc[mt], 0, 0, 0);
                }
            }
            #pragma unroll
            for (int mt = 0; mt < 8; ++mt)
                *(uint2v*)(myq + l15*QP_STRIDE + mt*16 + l4*4) =
                    (uint2v){pk2bf(qc[mt][0], qc[mt][1]), pk2bf(qc[mt][2], qc[mt][3])};
            #pragma unroll
            for (int kk = 0; kk < 4; ++kk)
                qb[sub][kk] = *(const short8*)(myq + l15*QP_STRIDE + kk*32 + l4*8);
        }
    }

    float4v o[4][7];
    #pragma unroll
    for (int sub = 0; sub < 4; ++sub)
        #pragma unroll
        for (int dt = 0; dt < 7; ++dt) o[sub][dt] = (float4v){0,0,0,0};
    float lsum[4] = {0.f, 0.f, 0.f, 0.f};

    const short* xrg = (const short*)xrow + (long)c*768*128;
    const short* xtg = (const short*)xT + (long)c*128*768;
    const int rl4 = lane >> 4, cp16 = lane & 15;
    const int rl8 = lane >> 3, cp8 = lane & 7;
    const int njt = (wave == 3) ? 2 : 4;

    for (int kt = 0; kt < 12; ++kt) {
        const int key0 = kt * 64;
        #pragma unroll
        for (int j = 0; j < 4; ++j) {
            int row = wave*16 + j*4 + rl4;
            int lc = cp16 ^ (row & 7);
            gload16(xrg + (long)(key0 + row)*128 + lc*8, xr + (wave*16 + j*4)*128);
        }
        for (int j = 0; j < njt; ++j) {
            int row = wave*32 + j*8 + rl8;
            int lc = cp8 ^ (row & 7);
            gload16(xtg + (long)row*768 + key0 + lc*8, xt + (wave*32 + j*8)*64);
        }
        __syncthreads();

        // S^T: 4 key-tiles x 4 subtiles; A-frags shared across subtiles
        #pragma unroll
        for (int kn = 0; kn < 4; ++kn) {
            float4v s[4];
            #pragma unroll
            for (int sub = 0; sub < 4; ++sub) s[sub] = (float4v){0,0,0,0};
            #pragma unroll
            for (int kk = 0; kk < 4; ++kk) {
                short8 a = *(const short8*)(xr + (kn*16 + l15)*128 + (((kk*4 + l4) ^ sw)*8));
                #pragma unroll
                for (int sub = 0; sub < 4; ++sub)
                    s[sub] = __builtin_amdgcn_mfma_f32_16x16x32_bf16(a, qb[sub][kk], s[sub], 0, 0, 0);
            }
            // p = exp(s) -> swizzled pt (write b64 at chunk (2kn+(l4>>1))^sw)
            #pragma unroll
            for (int sub = 0; sub < 4; ++sub) {
                float p0 = __expf(s[sub][0]), p1 = __expf(s[sub][1]);
                float p2 = __expf(s[sub][2]), p3 = __expf(s[sub][3]);
                lsum[sub] += (p0 + p1) + (p2 + p3);
                *(uint2v*)(scratch[wave] + sub*1024 + l15*64 +
                           (((2*kn + (l4 >> 1)) ^ sw)*8) + (l4 & 1)*4) =
                    (uint2v){pk2bf(p0, p1), pk2bf(p2, p3)};
            }
        }

        // O^T += xt(A) . P^T(B); A-frags shared across subtiles
        #pragma unroll
        for (int kk2 = 0; kk2 < 2; ++kk2) {
            short8 b[4];
            #pragma unroll
            for (int sub = 0; sub < 4; ++sub)
                b[sub] = *(const short8*)(scratch[wave] + sub*1024 + l15*64 +
                                          (((kk2*4 + l4) ^ sw)*8));
            #pragma unroll
            for (int dt = 0; dt < 7; ++dt) {
                short8 a = *(const short8*)(xt + (dt*16 + l15)*64 + (((kk2*4 + l4) ^ sw)*8));
                #pragma unroll
                for (int sub = 0; sub < 4; ++sub)
                    o[sub][dt] = __builtin_amdgcn_mfma_f32_16x16x32_bf16(a, b[sub], o[sub][dt], 0, 0, 0);
            }
        }
        __syncthreads();
    }

    // final l reduction (query = l15) and store
    #pragma unroll
    for (int sub = 0; sub < 4; ++sub) {
        float l = lsum[sub];
        l += __shfl_xor(l, 16, 64); l += __shfl_xor(l, 32, 64);
        float inv = 1.f / l;
        unsigned short* Wo = Wb + ((long)(c*768 + q0 + sub*64 + wave*16 + l15))*512 + h*100 + l4*4;
        #pragma unroll
        for (int dt = 0; dt < 7; ++dt) {
            if (dt < 6 || l4 == 0) {
                *(uint2v*)(Wo + dt*16) = (uint2v){pk2bf(o[sub][dt][0]*inv, o[sub][dt][1]*inv),
                                                  pk2bf(o[sub][dt][2]*inv, o[sub][dt][3]*inv)};
            }
        }
    }
    if (h == 0) {
        unsigned short* Wz = Wb + ((long)c*768 + q0)*512 + 500;
        for (int i = tid; i < 3072; i += 256) Wz[(long)(i/12)*512 + (i%12)] = 0;
    }
}

// ---------------- fused encoder tail: W@Ust + res + LN1 + FFN + res + LN2 (+ bf16 emit) ----
template<bool EMIT>
__global__ void __launch_bounds__(256) k_tail(const unsigned short* __restrict__ Wb,
        const unsigned short* __restrict__ UstT,
        const unsigned short* __restrict__ f1wT, const unsigned short* __restrict__ f2wT,
        const float* __restrict__ f1b, const float* __restrict__ f2b,
        const float* __restrict__ g1, const float* __restrict__ b1,
        const float* __restrict__ g2, const float* __restrict__ b2,
        float* __restrict__ x, unsigned short* __restrict__ xrow, unsigned short* __restrict__ xT) {
    __shared__ __align__(16) short zS[4][16*136];
    __shared__ __align__(16) short tS[4][16*72];
    const int tid = threadIdx.x, wave = tid >> 6, lane = tid & 63;
    const int l15 = lane & 15, l4 = lane >> 4;
    const long row = (long)blockIdx.x*64 + wave*16 + l15;
    const int cc = blockIdx.x / 12;
    const int tt = (blockIdx.x % 12)*64 + wave*16 + l15;
    short* myz = zS[wave];
    short* myt = tS[wave];

    const short* Wr = (const short*)Wb + row*512 + l4*8;
    float4v o[8];
    #pragma unroll
    for (int mt = 0; mt < 8; ++mt) o[mt] = (float4v){0,0,0,0};
    for (int ks = 0; ks < 16; ++ks) {
        short8 b = *(const short8*)(Wr + ks*32);
        #pragma unroll
        for (int mt = 0; mt < 8; ++mt) {
            short8 a = *(const short8*)((const short*)UstT + (long)(mt*16 + l15)*512 + ks*32 + l4*8);
            o[mt] = __builtin_amdgcn_mfma_f32_16x16x32_bf16(a, b, o[mt], 0, 0, 0);
        }
    }

    float zv[7][4];
    float sum = 0.f;
    #pragma unroll
    for (int mt = 0; mt < 7; ++mt) {
        int f0 = mt*16 + l4*4;
        float4 xv = {0,0,0,0};
        if (f0 < 100) xv = *(const float4*)(x + row*100 + f0);
        #pragma unroll
        for (int r = 0; r < 4; ++r) {
            float z = 0.f;
            if (f0 < 100) { z = o[mt][r] + ((const float*)&xv)[r]; sum += z; }
            zv[mt][r] = z;
        }
    }
    sum += __shfl_xor(sum, 16, 64); sum += __shfl_xor(sum, 32, 64);
    float mean = sum * 0.01f;
    float vs = 0.f;
    #pragma unroll
    for (int mt = 0; mt < 7; ++mt) {
        if (mt*16 + l4*4 < 100) {
            #pragma unroll
            for (int r = 0; r < 4; ++r) { float d = zv[mt][r] - mean; vs += d*d; }
        }
    }
    vs += __shfl_xor(vs, 16, 64); vs += __shfl_xor(vs, 32, 64);
    float inv = rsqrtf(vs * 0.01f + 1e-5f);
    float x1r[7][4];
    #pragma unroll
    for (int mt = 0; mt < 7; ++mt) {
        int f0 = mt*16 + l4*4;
        float4 gv = {0,0,0,0}, bv = {0,0,0,0};
        if (f0 < 100) { gv = *(const float4*)(g1 + f0); bv = *(const float4*)(b1 + f0); }
        #pragma unroll
        for (int r = 0; r < 4; ++r)
            x1r[mt][r] = (f0 < 100) ? (zv[mt][r] - mean) * inv * ((const float*)&gv)[r] + ((const float*)&bv)[r] : 0.f;
    }

    #pragma unroll
    for (int mt = 0; mt < 8; ++mt) {
        float v0 = (mt < 7) ? x1r[mt][0] : 0.f, v1 = (mt < 7) ? x1r[mt][1] : 0.f;
        float v2 = (mt < 7) ? x1r[mt][2] : 0.f, v3 = (mt < 7) ? x1r[mt][3] : 0.f;
        *(uint2v*)(myz + l15*136 + mt*16 + l4*4) = (uint2v){pk2bf(v0, v1), pk2bf(v2, v3)};
    }

    float4v t2[4];
    #pragma unroll
    for (int m2t = 0; m2t < 4; ++m2t) t2[m2t] = (float4v){0,0,0,0};
    #pragma unroll
    for (int ks = 0; ks < 4; ++ks) {
        short8 b = *(const short8*)(myz + l15*136 + ks*32 + l4*8);
        #pragma unroll
        for (int m2t = 0; m2t < 4; ++m2t) {
            short8 a = *(const short8*)((const short*)f1wT + (m2t*16 + l15)*128 + ks*32 + l4*8);
            t2[m2t] = __builtin_amdgcn_mfma_f32_16x16x32_bf16(a, b, t2[m2t], 0, 0, 0);
        }
    }
    #pragma unroll
    for (int m2t = 0; m2t < 4; ++m2t) {
        int m20 = m2t*16 + l4*4;
        float4 bv = *(const float4*)(f1b + m20);
        float v0 = fmaxf(t2[m2t][0] + ((const float*)&bv)[0], 0.f);
        float v1 = fmaxf(t2[m2t][1] + ((const float*)&bv)[1], 0.f);
        float v2 = fmaxf(t2[m2t][2] + ((const float*)&bv)[2], 0.f);
        float v3 = fmaxf(t2[m2t][3] + ((const float*)&bv)[3], 0.f);
        *(uint2v*)(myt + l15*72 + m20) = (uint2v){pk2bf(v0, v1), pk2bf(v2, v3)};
    }

    float4v o3[7];
    #pragma unroll
    for (int m3t = 0; m3t < 7; ++m3t) o3[m3t] = (float4v){0,0,0,0};
    #pragma unroll
    for (int ks2 = 0; ks2 < 2; ++ks2) {
        short8 b = *(const short8*)(myt + l15*72 + ks2*32 + l4*8);
        #pragma unroll
        for (int m3t = 0; m3t < 7; ++m3t) {
            short8 a = *(const short8*)((const short*)f2wT + (m3t*16 + l15)*64 + ks2*32 + l4*8);
            o3[m3t] = __builtin_amdgcn_mfma_f32_16x16x32_bf16(a, b, o3[m3t], 0, 0, 0);
        }
    }

    float z2[7][4];
    float sum2 = 0.f;
    #pragma unroll
    for (int m3t = 0; m3t < 7; ++m3t) {
        int f0 = m3t*16 + l4*4;
        float4 bv = {0,0,0,0};
        if (f0 < 100) bv = *(const float4*)(f2b + f0);
        #pragma unroll
        for (int r = 0; r < 4; ++r) {
            float z = 0.f;
            if (f0 < 100) { z = o3[m3t][r] + ((const float*)&bv)[r] + x1r[m3t][r]; sum2 += z; }
            z2[m3t][r] = z;
        }
    }
    sum2 += __shfl_xor(sum2, 16, 64); sum2 += __shfl_xor(sum2, 32, 64);
    float mean2 = sum2 * 0.01f;
    float vs2 = 0.f;
    #pragma unroll
    for (int m3t = 0; m3t < 7; ++m3t) {
        if (m3t*16 + l4*4 < 100) {
            #pragma unroll
            for (int r = 0; r < 4; ++r) { float d = z2[m3t][r] - mean2; vs2 += d*d; }
        }
    }
    vs2 += __shfl_xor(vs2, 16, 64); vs2 += __shfl_xor(vs2, 32, 64);
    float inv2 = rsqrtf(vs2 * 0.01f + 1e-5f);

    unsigned short* xTc = EMIT ? (xT + (long)cc*98304 + tt) : nullptr;
    #pragma unroll
    for (int m3t = 0; m3t < 7; ++m3t) {
        int f0 = m3t*16 + l4*4;
        if (f0 < 100) {
            float4 gv = *(const float4*)(g2 + f0);
            float4 bv = *(const float4*)(b2 + f0);
            float y[4];
            #pragma unroll
            for (int r = 0; r < 4; ++r)
                y[r] = (z2[m3t][r] - mean2) * inv2 * ((const float*)&gv)[r] + ((const float*)&bv)[r];
            *(float4*)(x + row*100 + f0) = (float4){y[0], y[1], y[2], y[3]};
            if (EMIT) {
                *(uint2v*)(xrow + row*128 + f0) = (uint2v){pk2bf(y[0], y[1]), pk2bf(y[2], y[3])};
                #pragma unroll
                for (int r = 0; r < 4; ++r)
                    xTc[(long)(f0 + r)*768] = f2bf(y[r]);
            }
        } else if (EMIT) {
            *(uint2v*)(xrow + row*128 + f0) = (uint2v){0u, 0u};
            #pragma unroll
            for (int r = 0; r < 4; ++r)
                if (f0 + r < 112) xTc[(long)(f0 + r)*768] = 0;
        }
    }
    if (EMIT) *(uint2v*)(xrow + row*128 + 112 + l4*4) = (uint2v){0u, 0u};
}

// ---------------- autoregressive predictor (composed linear map) ----------------
__global__ void __launch_bounds__(256) k_pred2(const float* __restrict__ xf,
        const float* __restrict__ Mp, const float* __restrict__ c0v,
        float* __restrict__ out) {
    int c = blockIdx.x, tid = threadIdx.x;
    __shared__ float Ml[10000];
    __shared__ float carry[100];
    for (int i = tid; i < 10000; i += 256) Ml[i] = Mp[i];
    if (tid < 100) carry[tid] = xf[((long)c*768 + 767)*100 + tid];
    __syncthreads();
    for (int s = 0; s < 10; ++s) {
        float pv = 0.f;
        if (tid < 100) {
            pv = c0v[tid];
            for (int d = 0; d < 100; ++d) pv += carry[d] * Ml[d*100 + tid];
            out[((long)c*10 + s)*100 + tid] = pv;
        }
        __syncthreads();
        if (tid < 100) carry[tid] = pv;
        __syncthreads();
    }
}

extern "C" void kernel_launch(void* const* d_in, const int* in_sizes, int n_in,
                              void* d_out, int out_size, void* d_ws, size_t ws_size,
                              hipStream_t stream) {
    const float* X    = (const float*)d_in[0];
    const float* A    = (const float*)d_in[1];
    const float* gw1  = (const float*)d_in[2];
    const float* gb1  = (const float*)d_in[3];
    const float* gw2  = (const float*)d_in[4];
    const float* gb2  = (const float*)d_in[5];
    const float* wq   = (const float*)d_in[6];
    const float* wk   = (const float*)d_in[7];
    const float* wv   = (const float*)d_in[8];
    const float* wm   = (const float*)d_in[9];
    const float* f1w  = (const float*)d_in[10];
    const float* f1b  = (const float*)d_in[11];
    const float* f2w  = (const float*)d_in[12];
    const float* f2b  = (const float*)d_in[13];
    const float* ln1g = (const float*)d_in[14];
    const float* ln1b = (const float*)d_in[15];
    const float* ln2g = (const float*)d_in[16];
    const float* ln2b = (const float*)d_in[17];
    const float* l1w  = (const float*)d_in[18];
    const float* l1b  = (const float*)d_in[19];
    const float* l2w  = (const float*)d_in[20];
    const float* l2b  = (const float*)d_in[21];
    (void)in_sizes; (void)n_in; (void)out_size; (void)ws_size;

    float* ws   = (float*)d_ws;
    float* adjh = ws + OFF_ADJ;
    float* x0   = ws + OFF_X0;
    float* x1   = ws + OFF_X1;
    float* hid  = ws + OFF_HID;
    unsigned short* xrow = (unsigned short*)(ws + OFF_XROW);
    unsigned short* xTb  = (unsigned short*)(ws + OFF_XT);
    unsigned short* Wbf  = (unsigned short*)(ws + OFF_WBF);
    unsigned short* MhT  = (unsigned short*)(ws + OFF_MHT);
    unsigned short* UstT = (unsigned short*)(ws + OFF_USTT);
    float* Mp   = ws + OFF_MP;
    float* c0v  = ws + OFF_C0;
    unsigned short* f1wT = (unsigned short*)(ws + OFF_F1WT);
    unsigned short* f2wT = (unsigned short*)(ws + OFF_F2WT);
    float* out  = (float*)d_out;

    k_adj<<<1, 1024, 0, stream>>>(A, adjh);
    k_mu2<<<500, 256, 0, stream>>>(wq, wk, wv, wm, l1w, l1b, l2w, l2b, f1w, f2w,
                                   MhT, UstT, Mp, c0v, f1wT, f2wT);

    // GCN
    k_spmm<<<300, 256, 0, stream>>>(adjh, X, x1, 76800);
    k_gemm<8, true, true><<<768, 256, 0, stream>>>(x1, gw1, gb1, hid, ROWS, 60, 100);
    k_spmm<<<180, 256, 0, stream>>>(adjh, hid, x1, 46080);
    k_gemm<13, false, true><<<768, 256, 0, stream>>>(x1, gw2, gb2, x0, ROWS, 100, 60);

    // encoder layers: attn + fused tail
    k_prep<<<dim3(12,32), 256, 0, stream>>>(x0, xrow, xTb);
    for (int l = 0; l < 3; ++l) {
        k_attn7<<<dim3(3,5,32), 256, 0, stream>>>(xrow, xTb, MhT + (long)l*81920, Wbf);
        if (l < 2)
            k_tail<true><<<384, 256, 0, stream>>>(Wbf, UstT + (long)l*65536,
                f1wT + (long)l*8192, f2wT + (long)l*7168, f1b + l*64, f2b + l*100,
                ln1g + l*100, ln1b + l*100, ln2g + l*100, ln2b + l*100, x0, xrow, xTb);
        else
            k_tail<false><<<384, 256, 0, stream>>>(Wbf, UstT + (long)l*65536,
                f1wT + (long)l*8192, f2wT + (long)l*7168, f1b + l*64, f2b + l*100,
                ln1g + l*100, ln1b + l*100, ln2g + l*100, ln2b + l*100, x0, xrow, xTb);
    }

    k_pred2<<<32, 256, 0, stream>>>(x0, Mp, c0v, out);
}

// Round 12
// 678.913 us; speedup vs baseline: 1.1272x; 1.1272x over previous
//
#include <hip/hip_runtime.h>

// GTA model: GCN(2-hop) -> 3x transformer encoder -> 10-step AR predictor.
// R11: attention with 512-thread blocks (8 waves x 2 subtiles = 256 q/block).
// Same per-wave register footprint as R9 (no spill - R10's failure mode was
// arch-VGPR spill from 4 subtiles/wave); staging shared by 8 waves; grid 480
// blocks, 2 blocks/CU, full residency. Q-scratch overlaid on pt (XOR swizzle).
// Tail fused per layer (R9).

#define ROWS 24576   // C*T = 32*768

// workspace offsets (floats)
#define OFF_ADJ   0L
#define OFF_X0    1024L
#define OFF_X1    (OFF_X0 + 2457600L)
#define OFF_HID   (OFF_X1 + 2457600L)
#define OFF_XROW  (OFF_HID + 1474560L)       // 24576*128 bf16 = 1572864 floats
#define OFF_XT    (OFF_XROW + 1572864L)
#define OFF_WBF   (OFF_XT + 1572864L)        // 24576*512 bf16 = 6291456 floats
#define OFF_MHT   (OFF_WBF + 6291456L)       // 15*128*128 bf16 = 122880 floats
#define OFF_USTT  (OFF_MHT + 122880L)        // 3*128*512 bf16 = 98304 floats
#define OFF_MP    (OFF_USTT + 98304L)        // 100*100 fp32
#define OFF_C0    (OFF_MP + 10000L)          // 100 fp32 (pad to 128)
#define OFF_F1WT  (OFF_C0 + 128L)            // 3*64*128 bf16 = 12288 floats
#define OFF_F2WT  (OFF_F1WT + 12288L)        // 3*112*64 bf16 = 10752 floats

typedef __attribute__((ext_vector_type(8))) short short8;
typedef __attribute__((ext_vector_type(4))) float float4v;
typedef __attribute__((ext_vector_type(2))) unsigned int uint2v;

__device__ inline unsigned short f2bf(float f) {
    unsigned u = __builtin_bit_cast(unsigned, f);
    return (unsigned short)((u + 0x7fffu + ((u >> 16) & 1u)) >> 16);
}
__device__ inline unsigned pk2bf(float lo, float hi) {
    return (unsigned)f2bf(lo) | ((unsigned)f2bf(hi) << 16);
}
// async global->LDS DMA, 16B per lane; LDS dest = wave-uniform base + lane*16
__device__ inline void gload16(const short* g, short* l) {
    __builtin_amdgcn_global_load_lds((const __attribute__((address_space(1))) void*)g,
                                     (__attribute__((address_space(3))) void*)l, 16, 0, 0);
}

// ---------------- adjacency normalization ----------------
__global__ void __launch_bounds__(1024) k_adj(const float* __restrict__ A, float* __restrict__ adjh) {
    __shared__ float adj[32][32];
    __shared__ float rs[32];
    int tid = threadIdx.x;
    int i = tid >> 5, j = tid & 31;
    float v = A[i*32 + j] + (i == j ? 1.f : 0.f);
    adj[i][j] = v;
    __syncthreads();
    if (tid < 32) {
        float s = 0.f;
        #pragma unroll
        for (int jj = 0; jj < 32; ++jj) s += adj[tid][jj];
        rs[tid] = s;
    }
    __syncthreads();
    adjh[i*32 + j] = adj[i][j] / rs[i];
}

// ---------------- precompute (parallel): MhT, UstT, f1wT, f2wT (bf16 padded), Mpred, c0 ----
__global__ void __launch_bounds__(256) k_mu2(const float* __restrict__ wq, const float* __restrict__ wk,
                                             const float* __restrict__ wv, const float* __restrict__ wm,
                                             const float* __restrict__ l1w, const float* __restrict__ l1b,
                                             const float* __restrict__ l2w, const float* __restrict__ l2b,
                                             const float* __restrict__ f1w, const float* __restrict__ f2w,
                                             unsigned short* __restrict__ MhT, unsigned short* __restrict__ UstT,
                                             float* __restrict__ Mp, float* __restrict__ c0v,
                                             unsigned short* __restrict__ f1wT, unsigned short* __restrict__ f2wT) {
    int bi = blockIdx.x, tid = threadIdx.x;
    if (bi < 480) {
        int mat = bi >> 4, sub = bi & 15;
        int mode = mat / 15, idx = mat % 15, l = idx / 5, h = idx % 5;
        const float* Asrc = (mode == 0 ? wq : wv) + (l*5 + h)*10000;
        const float* Bsrc = (mode == 0) ? (wk + (l*5 + h)*10000) : (wm + l*50000 + h*10000);
        int oend = sub*625 + 625;
        for (int o = sub*625 + tid; o < oend; o += 256) {
            int r = o / 100, cix = o - (o/100)*100;
            const float* arow = Asrc + r*100;
            float acc = 0.f;
            if (mode == 0) {
                const float* brow = Bsrc + cix*100;
                for (int e = 0; e < 100; ++e) acc += arow[e] * brow[e];
                MhT[(long)(l*5 + h)*16384 + cix*128 + r] = f2bf(acc * 0.1f);
            } else {
                for (int e = 0; e < 100; ++e) acc += arow[e] * Bsrc[e*100 + cix];
                UstT[(long)l*65536 + (long)cix*512 + h*100 + r] = f2bf(acc);
            }
        }
        if (sub == 0) {   // zero padding
            if (mode == 0) {
                unsigned short* M0 = MhT + (long)(l*5 + h)*16384;
                for (int i = tid; i < 28*128; i += 256) M0[(100 + i/128)*128 + (i%128)] = 0;
                for (int i = tid; i < 100*28; i += 256) M0[(i/28)*128 + 100 + (i%28)] = 0;
            } else if (h == 4) {
                unsigned short* U0 = UstT + (long)l*65536;
                for (int i = tid; i < 28*512; i += 256) U0[(long)(100 + i/512)*512 + (i%512)] = 0;
                for (int i = tid; i < 100*12; i += 256) U0[(long)(i/12)*512 + 500 + (i%12)] = 0;
            }
        }
    } else if (bi < 496) {
        int sub = bi - 480;
        int oend = sub*625 + 625;
        for (int o = sub*625 + tid; o < oend; o += 256) {
            int r = o / 100, cix = o - (o/100)*100;
            const float* arow = l1w + r*200;
            float acc = 0.f;
            for (int e = 0; e < 200; ++e) acc += arow[e] * l2w[e*100 + cix];
            Mp[r*100 + cix] = acc;
        }
    } else if (bi == 496) {
        if (tid < 100) {
            float acc = l2b[tid];
            for (int e = 0; e < 200; ++e) acc += l1b[e] * l2w[e*100 + tid];
            c0v[tid] = acc;
        }
    } else {
        int l = bi - 497;   // per-layer FFN weight transposes
        unsigned short* F1 = f1wT + (long)l*8192;
        for (int i = tid; i < 8192; i += 256) {
            int o = i >> 7, k = i & 127;
            F1[i] = (k < 100) ? f2bf(f1w[l*6400 + k*64 + o]) : (unsigned short)0;
        }
        unsigned short* F2 = f2wT + (long)l*7168;
        for (int i = tid; i < 7168; i += 256) {
            int o2 = i >> 6, k2 = i & 63;
            F2[i] = (o2 < 100) ? f2bf(f2w[l*6400 + k2*100 + o2]) : (unsigned short)0;
        }
    }
}

// ---------------- spmm: Y[i,f] = sum_j adjh[i,j] * Xin[j,f] ----------------
__global__ void __launch_bounds__(256) k_spmm(const float* __restrict__ adjh, const float* __restrict__ Xin,
                                              float* __restrict__ Y, int F) {
    __shared__ float adj[1024];
    int tid = threadIdx.x;
    for (int i = tid; i < 1024; i += 256) adj[i] = adjh[i];
    __syncthreads();
    long f = (long)blockIdx.x * 256 + tid;
    float acc[32];
    #pragma unroll
    for (int i = 0; i < 32; ++i) acc[i] = 0.f;
    for (int jj = 0; jj < 32; ++jj) {
        float xv = Xin[jj*(long)F + f];
        #pragma unroll
        for (int i = 0; i < 32; ++i) acc[i] += adj[i*32 + jj] * xv;
    }
    #pragma unroll
    for (int i = 0; i < 32; ++i) Y[i*(long)F + f] = acc[i];
}

// ---------------- fp32 tiled GEMM (GCN only) ----------------
template<int NCOLS, bool RELU, bool BIAS>
__global__ void __launch_bounds__(256) k_gemm(const float* __restrict__ A, const float* __restrict__ B,
                                              const float* __restrict__ bias, float* __restrict__ Cc,
                                              int M, int N, int K) {
    constexpr int NP = 8*NCOLS;
    int tid = threadIdx.x;
    int m0 = blockIdx.x * 32;
    int mloc = tid & 31, grp = tid >> 5;
    int n0 = grp * NCOLS;
    __shared__ float As[32][33];
    __shared__ float Bs[32][NP + 1];
    float acc[NCOLS];
    #pragma unroll
    for (int i2 = 0; i2 < NCOLS; ++i2) acc[i2] = 0.f;
    for (int k0 = 0; k0 < K; k0 += 32) {
        #pragma unroll
        for (int st = 0; st < 4; ++st) {
            int rr = (tid >> 5) + st*8, kk = tid & 31, gk = k0 + kk;
            As[rr][kk] = (gk < K) ? A[(long)(m0 + rr)*K + gk] : 0.f;
        }
        for (int i2 = tid; i2 < 32*NP; i2 += 256) {
            int kk = i2 / NP, nn = i2 - kk*NP;
            int gk = k0 + kk;
            Bs[kk][nn] = (gk < K && nn < N) ? B[(long)gk*N + nn] : 0.f;
        }
        __syncthreads();
        #pragma unroll 8
        for (int kk = 0; kk < 32; ++kk) {
            float a = As[mloc][kk];
            #pragma unroll
            for (int j2 = 0; j2 < NCOLS; ++j2) acc[j2] += a * Bs[kk][n0 + j2];
        }
        __syncthreads();
    }
    #pragma unroll
    for (int j2 = 0; j2 < NCOLS; ++j2) {
        int nn = n0 + j2;
        if (nn < N) {
            float v = acc[j2];
            if (BIAS) v += bias[nn];
            if (RELU) v = fmaxf(v, 0.f);
            Cc[(long)(m0 + mloc)*N + nn] = v;
        }
    }
}

// ---------------- x fp32 -> bf16 row-major [c][t][128] and transposed [c][128][t] ----------------
__global__ void __launch_bounds__(256) k_prep(const float* __restrict__ x, unsigned short* __restrict__ xrow,
                                              unsigned short* __restrict__ xT) {
    int c = blockIdx.y, t0 = blockIdx.x * 64;
    int tid = threadIdx.x;
    __shared__ float xs[64][101];
    const float* xp = x + ((long)c*768 + t0) * 100;
    for (int i = tid; i < 6400; i += 256) {
        int r = i / 100, d = i - r*100;
        xs[r][d] = xp[i];
    }
    __syncthreads();
    unsigned short* xro = xrow + ((long)c*768 + t0) * 128;
    for (int i = tid; i < 8192; i += 256) {
        int r = i >> 7, d = i & 127;
        xro[i] = (d < 100) ? f2bf(xs[r][d]) : (unsigned short)0;
    }
    unsigned short* xto = xT + (long)c*128*768 + t0;
    for (int i = tid; i < 8192; i += 256) {
        int d = i >> 6, t = i & 63;
        xto[(long)d*768 + t] = (d < 100) ? f2bf(xs[t][d]) : (unsigned short)0;
    }
}

// ---------------- fused Q-proj + flash attention, 8 waves x 2 subtiles (256 q/block) ----------
// grid (3, 5, 32); block 512. xr/xt DMA-staged, XOR-chunk swizzle. pt/Q scratch
// overlaid per wave: 2048 shorts, stride 64 (Q: stride 128), XOR-chunk swizzle.
__global__ void __launch_bounds__(512) k_attn8(const unsigned short* __restrict__ xrow,
                                               const unsigned short* __restrict__ xT,
                                               const unsigned short* __restrict__ MhT,
                                               unsigned short* __restrict__ Wb) {
    __shared__ __align__(16) short xr[64 * 128];            // 16384 B
    __shared__ __align__(16) short xt[112 * 64];            // 14336 B
    __shared__ __align__(16) short scratch[8][2048];        // 32768 B
    const int tid = threadIdx.x;
    const int wave = tid >> 6, lane = tid & 63;
    const int l15 = lane & 15, l4 = lane >> 4;
    const int c = blockIdx.z, h = blockIdx.y, q0 = blockIdx.x * 256;
    const int sw = l15 & 7;
    short* myp = scratch[wave];

    // ---- Q^T projection: 2 subtiles; transpose through swizzled wave-private scratch ----
    short8 qb0[4], qb1[4];
    {
        const short* Mb = (const short*)MhT + (long)h*16384 + l15*128 + l4*8;
        for (int sub = 0; sub < 2; ++sub) {
            const short* xq = (const short*)xrow +
                ((long)c*768 + q0 + sub*128 + wave*16 + l15)*128 + l4*8;
            short8 bq[4];
            #pragma unroll
            for (int kk = 0; kk < 4; ++kk) bq[kk] = *(const short8*)(xq + kk*32);
            float4v qc[8];
            #pragma unroll
            for (int mt = 0; mt < 8; ++mt) qc[mt] = (float4v){0,0,0,0};
            #pragma unroll
            for (int mt = 0; mt < 8; ++mt) {
                #pragma unroll
                for (int kk = 0; kk < 4; ++kk) {
                    short8 a = *(const short8*)(Mb + (mt*16)*128 + kk*32);
                    qc[mt] = __builtin_amdgcn_mfma_f32_16x16x32_bf16(a, bq[kk], qc[mt], 0, 0, 0);
                }
            }
            // write b64 at swizzled chunk (2mt + l4>>1)^sw, half (l4&1)
            #pragma unroll
            for (int mt = 0; mt < 8; ++mt)
                *(uint2v*)(myp + l15*128 + (((2*mt + (l4 >> 1)) ^ sw)*8) + (l4 & 1)*4) =
                    (uint2v){pk2bf(qc[mt][0], qc[mt][1]), pk2bf(qc[mt][2], qc[mt][3])};
            #pragma unroll
            for (int kk = 0; kk < 4; ++kk) {
                short8 q = *(const short8*)(myp + l15*128 + (((kk*4 + l4) ^ sw)*8));
                if (sub == 0) qb0[kk] = q; else qb1[kk] = q;
            }
        }
    }

    float4v o0[7], o1[7];
    #pragma unroll
    for (int dt = 0; dt < 7; ++dt) { o0[dt] = (float4v){0,0,0,0}; o1[dt] = (float4v){0,0,0,0}; }
    float lsum0 = 0.f, lsum1 = 0.f;

    const short* xrg = (const short*)xrow + (long)c*768*128;
    const short* xtg = (const short*)xT + (long)c*128*768;
    short* pt0 = scratch[wave];
    short* pt1 = scratch[wave] + 1024;

    for (int kt = 0; kt < 12; ++kt) {
        const int key0 = kt * 64;
        // xr: 1024 chunks, wave w -> [w*128, w*128+128), 2 DMA instrs
        #pragma unroll
        for (int i = 0; i < 2; ++i) {
            int ch = wave*128 + i*64 + lane;
            int row = ch >> 4, col = ch & 15;
            int lc = col ^ (row & 7);
            gload16(xrg + (long)(key0 + row)*128 + lc*8, xr + (wave*128 + i*64)*8);
        }
        // xt: 896 chunks, wave w -> [w*112, w*112+112)
        {
            int ch = wave*112 + lane;
            int row = ch >> 3, col = ch & 7;
            int lc = col ^ (row & 7);
            gload16(xtg + (long)row*768 + key0 + lc*8, xt + (wave*112)*8);
            if (lane < 48) {
                int ch2 = wave*112 + 64 + lane;
                int row2 = ch2 >> 3, col2 = ch2 & 7;
                int lc2 = col2 ^ (row2 & 7);
                gload16(xtg + (long)row2*768 + key0 + lc2*8, xt + (wave*112 + 64)*8);
            }
        }
        __syncthreads();

        // S^T: 4 key-tiles x 2 subtiles; xr A-frags shared
        #pragma unroll
        for (int kn = 0; kn < 4; ++kn) {
            float4v s0 = (float4v){0,0,0,0}, s1 = (float4v){0,0,0,0};
            #pragma unroll
            for (int kk = 0; kk < 4; ++kk) {
                short8 a = *(const short8*)(xr + (kn*16 + l15)*128 + (((kk*4 + l4) ^ sw)*8));
                s0 = __builtin_amdgcn_mfma_f32_16x16x32_bf16(a, qb0[kk], s0, 0, 0, 0);
                s1 = __builtin_amdgcn_mfma_f32_16x16x32_bf16(a, qb1[kk], s1, 0, 0, 0);
            }
            float p00 = __expf(s0[0]), p01 = __expf(s0[1]), p02 = __expf(s0[2]), p03 = __expf(s0[3]);
            float p10 = __expf(s1[0]), p11 = __expf(s1[1]), p12 = __expf(s1[2]), p13 = __expf(s1[3]);
            lsum0 += (p00 + p01) + (p02 + p03);
            lsum1 += (p10 + p11) + (p12 + p13);
            *(uint2v*)(pt0 + l15*64 + (((2*kn + (l4 >> 1)) ^ sw)*8) + (l4 & 1)*4) =
                (uint2v){pk2bf(p00, p01), pk2bf(p02, p03)};
            *(uint2v*)(pt1 + l15*64 + (((2*kn + (l4 >> 1)) ^ sw)*8) + (l4 & 1)*4) =
                (uint2v){pk2bf(p10, p11), pk2bf(p12, p13)};
        }

        // O^T += xt(A) . P^T(B); xt A-frags shared
        #pragma unroll
        for (int kk2 = 0; kk2 < 2; ++kk2) {
            short8 b0 = *(const short8*)(pt0 + l15*64 + (((kk2*4 + l4) ^ sw)*8));
            short8 b1 = *(const short8*)(pt1 + l15*64 + (((kk2*4 + l4) ^ sw)*8));
            #pragma unroll
            for (int dt = 0; dt < 7; ++dt) {
                short8 a = *(const short8*)(xt + (dt*16 + l15)*64 + (((kk2*4 + l4) ^ sw)*8));
                o0[dt] = __builtin_amdgcn_mfma_f32_16x16x32_bf16(a, b0, o0[dt], 0, 0, 0);
                o1[dt] = __builtin_amdgcn_mfma_f32_16x16x32_bf16(a, b1, o1[dt], 0, 0, 0);
            }
        }
        __syncthreads();
    }

    // final l reduction (query = l15) and store
    float l0 = lsum0, l1 = lsum1;
    l0 += __shfl_xor(l0, 16, 64); l0 += __shfl_xor(l0, 32, 64);
    l1 += __shfl_xor(l1, 16, 64); l1 += __shfl_xor(l1, 32, 64);
    float inv0 = 1.f / l0, inv1 = 1.f / l1;

    unsigned short* Wo0 = Wb + ((long)(c*768 + q0 + wave*16 + l15))*512 + h*100 + l4*4;
    unsigned short* Wo1 = Wo0 + 128*512;
    #pragma unroll
    for (int dt = 0; dt < 7; ++dt) {
        if (dt < 6 || l4 == 0) {
            *(uint2v*)(Wo0 + dt*16) = (uint2v){pk2bf(o0[dt][0]*inv0, o0[dt][1]*inv0),
                                               pk2bf(o0[dt][2]*inv0, o0[dt][3]*inv0)};
            *(uint2v*)(Wo1 + dt*16) = (uint2v){pk2bf(o1[dt][0]*inv1, o1[dt][1]*inv1),
                                               pk2bf(o1[dt][2]*inv1, o1[dt][3]*inv1)};
        }
    }
    if (h == 0) {
        unsigned short* Wz = Wb + ((long)c*768 + q0)*512 + 500;
        for (int i = tid; i < 3072; i += 512) Wz[(long)(i/12)*512 + (i%12)] = 0;
    }
}

// ---------------- fused encoder tail: W@Ust + res + LN1 + FFN + res + LN2 (+ bf16 emit) ----
template<bool EMIT>
__global__ void __launch_bounds__(256) k_tail(const unsigned short* __restrict__ Wb,
        const unsigned short* __restrict__ UstT,
        const unsigned short* __restrict__ f1wT, const unsigned short* __restrict__ f2wT,
        const float* __restrict__ f1b, const float* __restrict__ f2b,
        const float* __restrict__ g1, const float* __restrict__ b1,
        const float* __restrict__ g2, const float* __restrict__ b2,
        float* __restrict__ x, unsigned short* __restrict__ xrow, unsigned short* __restrict__ xT) {
    __shared__ __align__(16) short zS[4][16*136];
    __shared__ __align__(16) short tS[4][16*72];
    const int tid = threadIdx.x, wave = tid >> 6, lane = tid & 63;
    const int l15 = lane & 15, l4 = lane >> 4;
    const long row = (long)blockIdx.x*64 + wave*16 + l15;
    const int cc = blockIdx.x / 12;
    const int tt = (blockIdx.x % 12)*64 + wave*16 + l15;
    short* myz = zS[wave];
    short* myt = tS[wave];

    const short* Wr = (const short*)Wb + row*512 + l4*8;
    float4v o[8];
    #pragma unroll
    for (int mt = 0; mt < 8; ++mt) o[mt] = (float4v){0,0,0,0};
    for (int ks = 0; ks < 16; ++ks) {
        short8 b = *(const short8*)(Wr + ks*32);
        #pragma unroll
        for (int mt = 0; mt < 8; ++mt) {
            short8 a = *(const short8*)((const short*)UstT + (long)(mt*16 + l15)*512 + ks*32 + l4*8);
            o[mt] = __builtin_amdgcn_mfma_f32_16x16x32_bf16(a, b, o[mt], 0, 0, 0);
        }
    }

    float zv[7][4];
    float sum = 0.f;
    #pragma unroll
    for (int mt = 0; mt < 7; ++mt) {
        int f0 = mt*16 + l4*4;
        float4 xv = {0,0,0,0};
        if (f0 < 100) xv = *(const float4*)(x + row*100 + f0);
        #pragma unroll
        for (int r = 0; r < 4; ++r) {
            float z = 0.f;
            if (f0 < 100) { z = o[mt][r] + ((const float*)&xv)[r]; sum += z; }
            zv[mt][r] = z;
        }
    }
    sum += __shfl_xor(sum, 16, 64); sum += __shfl_xor(sum, 32, 64);
    float mean = sum * 0.01f;
    float vs = 0.f;
    #pragma unroll
    for (int mt = 0; mt < 7; ++mt) {
        if (mt*16 + l4*4 < 100) {
            #pragma unroll
            for (int r = 0; r < 4; ++r) { float d = zv[mt][r] - mean; vs += d*d; }
        }
    }
    vs += __shfl_xor(vs, 16, 64); vs += __shfl_xor(vs, 32, 64);
    float inv = rsqrtf(vs * 0.01f + 1e-5f);
    float x1r[7][4];
    #pragma unroll
    for (int mt = 0; mt < 7; ++mt) {
        int f0 = mt*16 + l4*4;
        float4 gv = {0,0,0,0}, bv = {0,0,0,0};
        if (f0 < 100) { gv = *(const float4*)(g1 + f0); bv = *(const float4*)(b1 + f0); }
        #pragma unroll
        for (int r = 0; r < 4; ++r)
            x1r[mt][r] = (f0 < 100) ? (zv[mt][r] - mean) * inv * ((const float*)&gv)[r] + ((const float*)&bv)[r] : 0.f;
    }

    #pragma unroll
    for (int mt = 0; mt < 8; ++mt) {
        float v0 = (mt < 7) ? x1r[mt][0] : 0.f, v1 = (mt < 7) ? x1r[mt][1] : 0.f;
        float v2 = (mt < 7) ? x1r[mt][2] : 0.f, v3 = (mt < 7) ? x1r[mt][3] : 0.f;
        *(uint2v*)(myz + l15*136 + mt*16 + l4*4) = (uint2v){pk2bf(v0, v1), pk2bf(v2, v3)};
    }

    float4v t2[4];
    #pragma unroll
    for (int m2t = 0; m2t < 4; ++m2t) t2[m2t] = (float4v){0,0,0,0};
    #pragma unroll
    for (int ks = 0; ks < 4; ++ks) {
        short8 b = *(const short8*)(myz + l15*136 + ks*32 + l4*8);
        #pragma unroll
        for (int m2t = 0; m2t < 4; ++m2t) {
            short8 a = *(const short8*)((const short*)f1wT + (m2t*16 + l15)*128 + ks*32 + l4*8);
            t2[m2t] = __builtin_amdgcn_mfma_f32_16x16x32_bf16(a, b, t2[m2t], 0, 0, 0);
        }
    }
    #pragma unroll
    for (int m2t = 0; m2t < 4; ++m2t) {
        int m20 = m2t*16 + l4*4;
        float4 bv = *(const float4*)(f1b + m20);
        float v0 = fmaxf(t2[m2t][0] + ((const float*)&bv)[0], 0.f);
        float v1 = fmaxf(t2[m2t][1] + ((const float*)&bv)[1], 0.f);
        float v2 = fmaxf(t2[m2t][2] + ((const float*)&bv)[2], 0.f);
        float v3 = fmaxf(t2[m2t][3] + ((const float*)&bv)[3], 0.f);
        *(uint2v*)(myt + l15*72 + m20) = (uint2v){pk2bf(v0, v1), pk2bf(v2, v3)};
    }

    float4v o3[7];
    #pragma unroll
    for (int m3t = 0; m3t < 7; ++m3t) o3[m3t] = (float4v){0,0,0,0};
    #pragma unroll
    for (int ks2 = 0; ks2 < 2; ++ks2) {
        short8 b = *(const short8*)(myt + l15*72 + ks2*32 + l4*8);
        #pragma unroll
        for (int m3t = 0; m3t < 7; ++m3t) {
            short8 a = *(const short8*)((const short*)f2wT + (m3t*16 + l15)*64 + ks2*32 + l4*8);
            o3[m3t] = __builtin_amdgcn_mfma_f32_16x16x32_bf16(a, b, o3[m3t], 0, 0, 0);
        }
    }

    float z2[7][4];
    float sum2 = 0.f;
    #pragma unroll
    for (int m3t = 0; m3t < 7; ++m3t) {
        int f0 = m3t*16 + l4*4;
        float4 bv = {0,0,0,0};
        if (f0 < 100) bv = *(const float4*)(f2b + f0);
        #pragma unroll
        for (int r = 0; r < 4; ++r) {
            float z = 0.f;
            if (f0 < 100) { z = o3[m3t][r] + ((const float*)&bv)[r] + x1r[m3t][r]; sum2 += z; }
            z2[m3t][r] = z;
        }
    }
    sum2 += __shfl_xor(sum2, 16, 64); sum2 += __shfl_xor(sum2, 32, 64);
    float mean2 = sum2 * 0.01f;
    float vs2 = 0.f;
    #pragma unroll
    for (int m3t = 0; m3t < 7; ++m3t) {
        if (m3t*16 + l4*4 < 100) {
            #pragma unroll
            for (int r = 0; r < 4; ++r) { float d = z2[m3t][r] - mean2; vs2 += d*d; }
        }
    }
    vs2 += __shfl_xor(vs2, 16, 64); vs2 += __shfl_xor(vs2, 32, 64);
    float inv2 = rsqrtf(vs2 * 0.01f + 1e-5f);

    unsigned short* xTc = EMIT ? (xT + (long)cc*98304 + tt) : nullptr;
    #pragma unroll
    for (int m3t = 0; m3t < 7; ++m3t) {
        int f0 = m3t*16 + l4*4;
        if (f0 < 100) {
            float4 gv = *(const float4*)(g2 + f0);
            float4 bv = *(const float4*)(b2 + f0);
            float y[4];
            #pragma unroll
            for (int r = 0; r < 4; ++r)
                y[r] = (z2[m3t][r] - mean2) * inv2 * ((const float*)&gv)[r] + ((const float*)&bv)[r];
            *(float4*)(x + row*100 + f0) = (float4){y[0], y[1], y[2], y[3]};
            if (EMIT) {
                *(uint2v*)(xrow + row*128 + f0) = (uint2v){pk2bf(y[0], y[1]), pk2bf(y[2], y[3])};
                #pragma unroll
                for (int r = 0; r < 4; ++r)
                    xTc[(long)(f0 + r)*768] = f2bf(y[r]);
            }
        } else if (EMIT) {
            *(uint2v*)(xrow + row*128 + f0) = (uint2v){0u, 0u};
            #pragma unroll
            for (int r = 0; r < 4; ++r)
                if (f0 + r < 112) xTc[(long)(f0 + r)*768] = 0;
        }
    }
    if (EMIT) *(uint2v*)(xrow + row*128 + 112 + l4*4) = (uint2v){0u, 0u};
}

// ---------------- autoregressive predictor (composed linear map) ----------------
__global__ void __launch_bounds__(256) k_pred2(const float* __restrict__ xf,
        const float* __restrict__ Mp, const float* __restrict__ c0v,
        float* __restrict__ out) {
    int c = blockIdx.x, tid = threadIdx.x;
    __shared__ float Ml[10000];
    __shared__ float carry[100];
    for (int i = tid; i < 10000; i += 256) Ml[i] = Mp[i];
    if (tid < 100) carry[tid] = xf[((long)c*768 + 767)*100 + tid];
    __syncthreads();
    for (int s = 0; s < 10; ++s) {
        float pv = 0.f;
        if (tid < 100) {
            pv = c0v[tid];
            for (int d = 0; d < 100; ++d) pv += carry[d] * Ml[d*100 + tid];
            out[((long)c*10 + s)*100 + tid] = pv;
        }
        __syncthreads();
        if (tid < 100) carry[tid] = pv;
        __syncthreads();
    }
}

extern "C" void kernel_launch(void* const* d_in, const int* in_sizes, int n_in,
                              void* d_out, int out_size, void* d_ws, size_t ws_size,
                              hipStream_t stream) {
    const float* X    = (const float*)d_in[0];
    const float* A    = (const float*)d_in[1];
    const float* gw1  = (const float*)d_in[2];
    const float* gb1  = (const float*)d_in[3];
    const float* gw2  = (const float*)d_in[4];
    const float* gb2  = (const float*)d_in[5];
    const float* wq   = (const float*)d_in[6];
    const float* wk   = (const float*)d_in[7];
    const float* wv   = (const float*)d_in[8];
    const float* wm   = (const float*)d_in[9];
    const float* f1w  = (const float*)d_in[10];
    const float* f1b  = (const float*)d_in[11];
    const float* f2w  = (const float*)d_in[12];
    const float* f2b  = (const float*)d_in[13];
    const float* ln1g = (const float*)d_in[14];
    const float* ln1b = (const float*)d_in[15];
    const float* ln2g = (const float*)d_in[16];
    const float* ln2b = (const float*)d_in[17];
    const float* l1w  = (const float*)d_in[18];
    const float* l1b  = (const float*)d_in[19];
    const float* l2w  = (const float*)d_in[20];
    const float* l2b  = (const float*)d_in[21];
    (void)in_sizes; (void)n_in; (void)out_size; (void)ws_size;

    float* ws   = (float*)d_ws;
    float* adjh = ws + OFF_ADJ;
    float* x0   = ws + OFF_X0;
    float* x1   = ws + OFF_X1;
    float* hid  = ws + OFF_HID;
    unsigned short* xrow = (unsigned short*)(ws + OFF_XROW);
    unsigned short* xTb  = (unsigned short*)(ws + OFF_XT);
    unsigned short* Wbf  = (unsigned short*)(ws + OFF_WBF);
    unsigned short* MhT  = (unsigned short*)(ws + OFF_MHT);
    unsigned short* UstT = (unsigned short*)(ws + OFF_USTT);
    float* Mp   = ws + OFF_MP;
    float* c0v  = ws + OFF_C0;
    unsigned short* f1wT = (unsigned short*)(ws + OFF_F1WT);
    unsigned short* f2wT = (unsigned short*)(ws + OFF_F2WT);
    float* out  = (float*)d_out;

    k_adj<<<1, 1024, 0, stream>>>(A, adjh);
    k_mu2<<<500, 256, 0, stream>>>(wq, wk, wv, wm, l1w, l1b, l2w, l2b, f1w, f2w,
                                   MhT, UstT, Mp, c0v, f1wT, f2wT);

    // GCN
    k_spmm<<<300, 256, 0, stream>>>(adjh, X, x1, 76800);
    k_gemm<8, true, true><<<768, 256, 0, stream>>>(x1, gw1, gb1, hid, ROWS, 60, 100);
    k_spmm<<<180, 256, 0, stream>>>(adjh, hid, x1, 46080);
    k_gemm<13, false, true><<<768, 256, 0, stream>>>(x1, gw2, gb2, x0, ROWS, 100, 60);

    // encoder layers: attn + fused tail
    k_prep<<<dim3(12,32), 256, 0, stream>>>(x0, xrow, xTb);
    for (int l = 0; l < 3; ++l) {
        k_attn8<<<dim3(3,5,32), 512, 0, stream>>>(xrow, xTb, MhT + (long)l*81920, Wbf);
        if (l < 2)
            k_tail<true><<<384, 256, 0, stream>>>(Wbf, UstT + (long)l*65536,
                f1wT + (long)l*8192, f2wT + (long)l*7168, f1b + l*64, f2b + l*100,
                ln1g + l*100, ln1b + l*100, ln2g + l*100, ln2b + l*100, x0, xrow, xTb);
        else
            k_tail<false><<<384, 256, 0, stream>>>(Wbf, UstT + (long)l*65536,
                f1wT + (long)l*8192, f2wT + (long)l*7168, f1b + l*64, f2b + l*100,
                ln1g + l*100, ln1b + l*100, ln2g + l*100, ln2b + l*100, x0, xrow, xTb);
    }

    k_pred2<<<32, 256, 0, stream>>>(x0, Mp, c0v, out);
}

// Round 13
// 591.176 us; speedup vs baseline: 1.2945x; 1.1484x over previous
//
#include <hip/hip_runtime.h>

// GTA model: GCN(2-hop) -> 3x transformer encoder -> 10-step AR predictor.
// R12: revert attention to R9's k_attn6 (4 waves/64-key tiles/960 blocks) --
// R10 (4 subtiles/wave, VGPR spill) and R11 (8-wave blocks, barrier-group
// stall) both proved the 87us structure is barrier-structural, not resource-
// bound. k_adj folded into k_mu2 (one fewer dispatch). Tail fused (R9).

#define ROWS 24576   // C*T = 32*768

// workspace offsets (floats)
#define OFF_ADJ   0L
#define OFF_X0    1024L
#define OFF_X1    (OFF_X0 + 2457600L)
#define OFF_HID   (OFF_X1 + 2457600L)
#define OFF_XROW  (OFF_HID + 1474560L)       // 24576*128 bf16 = 1572864 floats
#define OFF_XT    (OFF_XROW + 1572864L)
#define OFF_WBF   (OFF_XT + 1572864L)        // 24576*512 bf16 = 6291456 floats
#define OFF_MHT   (OFF_WBF + 6291456L)       // 15*128*128 bf16 = 122880 floats
#define OFF_USTT  (OFF_MHT + 122880L)        // 3*128*512 bf16 = 98304 floats
#define OFF_MP    (OFF_USTT + 98304L)        // 100*100 fp32
#define OFF_C0    (OFF_MP + 10000L)          // 100 fp32 (pad to 128)
#define OFF_F1WT  (OFF_C0 + 128L)            // 3*64*128 bf16 = 12288 floats
#define OFF_F2WT  (OFF_F1WT + 12288L)        // 3*112*64 bf16 = 10752 floats

typedef __attribute__((ext_vector_type(8))) short short8;
typedef __attribute__((ext_vector_type(4))) float float4v;
typedef __attribute__((ext_vector_type(2))) unsigned int uint2v;

__device__ inline unsigned short f2bf(float f) {
    unsigned u = __builtin_bit_cast(unsigned, f);
    return (unsigned short)((u + 0x7fffu + ((u >> 16) & 1u)) >> 16);
}
__device__ inline unsigned pk2bf(float lo, float hi) {
    return (unsigned)f2bf(lo) | ((unsigned)f2bf(hi) << 16);
}
// async global->LDS DMA, 16B per lane; LDS dest = wave-uniform base + lane*16
__device__ inline void gload16(const short* g, short* l) {
    __builtin_amdgcn_global_load_lds((const __attribute__((address_space(1))) void*)g,
                                     (__attribute__((address_space(3))) void*)l, 16, 0, 0);
}

// ---------------- precompute: MhT, UstT, f1wT, f2wT (bf16 padded), Mpred, c0, adjh ----
__global__ void __launch_bounds__(256) k_mu2(const float* __restrict__ wq, const float* __restrict__ wk,
                                             const float* __restrict__ wv, const float* __restrict__ wm,
                                             const float* __restrict__ l1w, const float* __restrict__ l1b,
                                             const float* __restrict__ l2w, const float* __restrict__ l2b,
                                             const float* __restrict__ f1w, const float* __restrict__ f2w,
                                             const float* __restrict__ A,
                                             unsigned short* __restrict__ MhT, unsigned short* __restrict__ UstT,
                                             float* __restrict__ Mp, float* __restrict__ c0v,
                                             unsigned short* __restrict__ f1wT, unsigned short* __restrict__ f2wT,
                                             float* __restrict__ adjh) {
    int bi = blockIdx.x, tid = threadIdx.x;
    if (bi < 480) {
        int mat = bi >> 4, sub = bi & 15;
        int mode = mat / 15, idx = mat % 15, l = idx / 5, h = idx % 5;
        const float* Asrc = (mode == 0 ? wq : wv) + (l*5 + h)*10000;
        const float* Bsrc = (mode == 0) ? (wk + (l*5 + h)*10000) : (wm + l*50000 + h*10000);
        int oend = sub*625 + 625;
        for (int o = sub*625 + tid; o < oend; o += 256) {
            int r = o / 100, cix = o - (o/100)*100;
            const float* arow = Asrc + r*100;
            float acc = 0.f;
            if (mode == 0) {
                const float* brow = Bsrc + cix*100;
                for (int e = 0; e < 100; ++e) acc += arow[e] * brow[e];
                MhT[(long)(l*5 + h)*16384 + cix*128 + r] = f2bf(acc * 0.1f);
            } else {
                for (int e = 0; e < 100; ++e) acc += arow[e] * Bsrc[e*100 + cix];
                UstT[(long)l*65536 + (long)cix*512 + h*100 + r] = f2bf(acc);
            }
        }
        if (sub == 0) {   // zero padding
            if (mode == 0) {
                unsigned short* M0 = MhT + (long)(l*5 + h)*16384;
                for (int i = tid; i < 28*128; i += 256) M0[(100 + i/128)*128 + (i%128)] = 0;
                for (int i = tid; i < 100*28; i += 256) M0[(i/28)*128 + 100 + (i%28)] = 0;
            } else if (h == 4) {
                unsigned short* U0 = UstT + (long)l*65536;
                for (int i = tid; i < 28*512; i += 256) U0[(long)(100 + i/512)*512 + (i%512)] = 0;
                for (int i = tid; i < 100*12; i += 256) U0[(long)(i/12)*512 + 500 + (i%12)] = 0;
            }
        }
    } else if (bi < 496) {
        int sub = bi - 480;
        int oend = sub*625 + 625;
        for (int o = sub*625 + tid; o < oend; o += 256) {
            int r = o / 100, cix = o - (o/100)*100;
            const float* arow = l1w + r*200;
            float acc = 0.f;
            for (int e = 0; e < 200; ++e) acc += arow[e] * l2w[e*100 + cix];
            Mp[r*100 + cix] = acc;
        }
    } else if (bi == 496) {
        if (tid < 100) {
            float acc = l2b[tid];
            for (int e = 0; e < 200; ++e) acc += l1b[e] * l2w[e*100 + tid];
            c0v[tid] = acc;
        }
    } else if (bi < 500) {
        int l = bi - 497;   // per-layer FFN weight transposes
        unsigned short* F1 = f1wT + (long)l*8192;
        for (int i = tid; i < 8192; i += 256) {
            int o = i >> 7, k = i & 127;
            F1[i] = (k < 100) ? f2bf(f1w[l*6400 + k*64 + o]) : (unsigned short)0;
        }
        unsigned short* F2 = f2wT + (long)l*7168;
        for (int i = tid; i < 7168; i += 256) {
            int o2 = i >> 6, k2 = i & 63;
            F2[i] = (o2 < 100) ? f2bf(f2w[l*6400 + k2*100 + o2]) : (unsigned short)0;
        }
    } else {
        // adjacency normalization (was k_adj)
        __shared__ float adj[1024];
        __shared__ float rs[32];
        for (int i = tid; i < 1024; i += 256) {
            int r = i >> 5, j = i & 31;
            adj[i] = A[i] + (r == j ? 1.f : 0.f);
        }
        __syncthreads();
        if (tid < 32) {
            float s = 0.f;
            #pragma unroll
            for (int jj = 0; jj < 32; ++jj) s += adj[tid*32 + jj];
            rs[tid] = s;
        }
        __syncthreads();
        for (int i = tid; i < 1024; i += 256) adjh[i] = adj[i] / rs[i >> 5];
    }
}

// ---------------- spmm: Y[i,f] = sum_j adjh[i,j] * Xin[j,f] ----------------
__global__ void __launch_bounds__(256) k_spmm(const float* __restrict__ adjh, const float* __restrict__ Xin,
                                              float* __restrict__ Y, int F) {
    __shared__ float adj[1024];
    int tid = threadIdx.x;
    for (int i = tid; i < 1024; i += 256) adj[i] = adjh[i];
    __syncthreads();
    long f = (long)blockIdx.x * 256 + tid;
    float acc[32];
    #pragma unroll
    for (int i = 0; i < 32; ++i) acc[i] = 0.f;
    for (int jj = 0; jj < 32; ++jj) {
        float xv = Xin[jj*(long)F + f];
        #pragma unroll
        for (int i = 0; i < 32; ++i) acc[i] += adj[i*32 + jj] * xv;
    }
    #pragma unroll
    for (int i = 0; i < 32; ++i) Y[i*(long)F + f] = acc[i];
}

// ---------------- fp32 tiled GEMM (GCN only) ----------------
template<int NCOLS, bool RELU, bool BIAS>
__global__ void __launch_bounds__(256) k_gemm(const float* __restrict__ A, const float* __restrict__ B,
                                              const float* __restrict__ bias, float* __restrict__ Cc,
                                              int M, int N, int K) {
    constexpr int NP = 8*NCOLS;
    int tid = threadIdx.x;
    int m0 = blockIdx.x * 32;
    int mloc = tid & 31, grp = tid >> 5;
    int n0 = grp * NCOLS;
    __shared__ float As[32][33];
    __shared__ float Bs[32][NP + 1];
    float acc[NCOLS];
    #pragma unroll
    for (int i2 = 0; i2 < NCOLS; ++i2) acc[i2] = 0.f;
    for (int k0 = 0; k0 < K; k0 += 32) {
        #pragma unroll
        for (int st = 0; st < 4; ++st) {
            int rr = (tid >> 5) + st*8, kk = tid & 31, gk = k0 + kk;
            As[rr][kk] = (gk < K) ? A[(long)(m0 + rr)*K + gk] : 0.f;
        }
        for (int i2 = tid; i2 < 32*NP; i2 += 256) {
            int kk = i2 / NP, nn = i2 - kk*NP;
            int gk = k0 + kk;
            Bs[kk][nn] = (gk < K && nn < N) ? B[(long)gk*N + nn] : 0.f;
        }
        __syncthreads();
        #pragma unroll 8
        for (int kk = 0; kk < 32; ++kk) {
            float a = As[mloc][kk];
            #pragma unroll
            for (int j2 = 0; j2 < NCOLS; ++j2) acc[j2] += a * Bs[kk][n0 + j2];
        }
        __syncthreads();
    }
    #pragma unroll
    for (int j2 = 0; j2 < NCOLS; ++j2) {
        int nn = n0 + j2;
        if (nn < N) {
            float v = acc[j2];
            if (BIAS) v += bias[nn];
            if (RELU) v = fmaxf(v, 0.f);
            Cc[(long)(m0 + mloc)*N + nn] = v;
        }
    }
}

// ---------------- x fp32 -> bf16 row-major [c][t][128] and transposed [c][128][t] ----------------
__global__ void __launch_bounds__(256) k_prep(const float* __restrict__ x, unsigned short* __restrict__ xrow,
                                              unsigned short* __restrict__ xT) {
    int c = blockIdx.y, t0 = blockIdx.x * 64;
    int tid = threadIdx.x;
    __shared__ float xs[64][101];
    const float* xp = x + ((long)c*768 + t0) * 100;
    for (int i = tid; i < 6400; i += 256) {
        int r = i / 100, d = i - r*100;
        xs[r][d] = xp[i];
    }
    __syncthreads();
    unsigned short* xro = xrow + ((long)c*768 + t0) * 128;
    for (int i = tid; i < 8192; i += 256) {
        int r = i >> 7, d = i & 127;
        xro[i] = (d < 100) ? f2bf(xs[r][d]) : (unsigned short)0;
    }
    unsigned short* xto = xT + (long)c*128*768 + t0;
    for (int i = tid; i < 8192; i += 256) {
        int d = i >> 6, t = i & 63;
        xto[(long)d*768 + t] = (d < 100) ? f2bf(xs[t][d]) : (unsigned short)0;
    }
}

// ---------------- fused Q-proj + flash attention, DMA-staged swizzled LDS (R9) ----------------
#define QP_STRIDE 136
#define PT_STRIDE 72

__global__ void __launch_bounds__(256) k_attn6(const unsigned short* __restrict__ xrow,
                                               const unsigned short* __restrict__ xT,
                                               const unsigned short* __restrict__ MhT,
                                               unsigned short* __restrict__ Wb) {
    __shared__ __align__(16) short xr[64 * 128];
    __shared__ __align__(16) short xt[112 * 64];
    __shared__ __align__(16) short scratch[4][2304];
    const int tid = threadIdx.x;
    const int wave = tid >> 6, lane = tid & 63;
    const int l15 = lane & 15, l4 = lane >> 4;
    const int c = blockIdx.z, h = blockIdx.y, q0 = blockIdx.x * 128;
    short* myq = scratch[wave];
    short* pt0 = scratch[wave];
    short* pt1 = scratch[wave] + 1152;

    short8 qb0[4], qb1[4];
    {
        const short* xq = (const short*)xrow + ((long)c*768 + q0 + wave*16 + l15)*128 + l4*8;
        short8 bq0[4], bq1[4];
        #pragma unroll
        for (int kk = 0; kk < 4; ++kk) {
            bq0[kk] = *(const short8*)(xq + kk*32);
            bq1[kk] = *(const short8*)(xq + 64*128 + kk*32);
        }
        const short* Mb = (const short*)MhT + (long)h*16384 + l15*128 + l4*8;
        float4v qc0[8], qc1[8];
        #pragma unroll
        for (int mt = 0; mt < 8; ++mt) { qc0[mt] = (float4v){0,0,0,0}; qc1[mt] = (float4v){0,0,0,0}; }
        #pragma unroll
        for (int mt = 0; mt < 8; ++mt) {
            #pragma unroll
            for (int kk = 0; kk < 4; ++kk) {
                short8 a = *(const short8*)(Mb + (mt*16)*128 + kk*32);
                qc0[mt] = __builtin_amdgcn_mfma_f32_16x16x32_bf16(a, bq0[kk], qc0[mt], 0, 0, 0);
                qc1[mt] = __builtin_amdgcn_mfma_f32_16x16x32_bf16(a, bq1[kk], qc1[mt], 0, 0, 0);
            }
        }
        #pragma unroll
        for (int mt = 0; mt < 8; ++mt)
            *(uint2v*)(myq + l15*QP_STRIDE + mt*16 + l4*4) =
                (uint2v){pk2bf(qc0[mt][0], qc0[mt][1]), pk2bf(qc0[mt][2], qc0[mt][3])};
        #pragma unroll
        for (int kk = 0; kk < 4; ++kk) qb0[kk] = *(const short8*)(myq + l15*QP_STRIDE + kk*32 + l4*8);
        #pragma unroll
        for (int mt = 0; mt < 8; ++mt)
            *(uint2v*)(myq + l15*QP_STRIDE + mt*16 + l4*4) =
                (uint2v){pk2bf(qc1[mt][0], qc1[mt][1]), pk2bf(qc1[mt][2], qc1[mt][3])};
        #pragma unroll
        for (int kk = 0; kk < 4; ++kk) qb1[kk] = *(const short8*)(myq + l15*QP_STRIDE + kk*32 + l4*8);
    }

    float4v o0[7], o1[7];
    #pragma unroll
    for (int n = 0; n < 7; ++n) { o0[n] = (float4v){0,0,0,0}; o1[n] = (float4v){0,0,0,0}; }
    float lsum0 = 0.f, lsum1 = 0.f;

    const short* xrg = (const short*)xrow + (long)c*768*128;
    const short* xtg = (const short*)xT + (long)c*128*768;
    const int rl4 = lane >> 4, cp16 = lane & 15;
    const int rl8 = lane >> 3, cp8 = lane & 7;
    const int njt = (wave == 3) ? 2 : 4;

    for (int kt = 0; kt < 12; ++kt) {
        const int key0 = kt * 64;
        #pragma unroll
        for (int j = 0; j < 4; ++j) {
            int row = wave*16 + j*4 + rl4;
            int lc = cp16 ^ (row & 7);
            gload16(xrg + (long)(key0 + row)*128 + lc*8, xr + (wave*16 + j*4)*128);
        }
        for (int j = 0; j < njt; ++j) {
            int row = wave*32 + j*8 + rl8;
            int lc = cp8 ^ (row & 7);
            gload16(xtg + (long)row*768 + key0 + lc*8, xt + (wave*32 + j*8)*64);
        }
        __syncthreads();

        float4v s0[4], s1[4];
        #pragma unroll
        for (int kn = 0; kn < 4; ++kn) { s0[kn] = (float4v){0,0,0,0}; s1[kn] = (float4v){0,0,0,0}; }
        #pragma unroll
        for (int kn = 0; kn < 4; ++kn) {
            #pragma unroll
            for (int kk = 0; kk < 4; ++kk) {
                short8 a = *(const short8*)(xr + (kn*16 + l15)*128 + (((kk*4 + l4) ^ (l15 & 7))*8));
                s0[kn] = __builtin_amdgcn_mfma_f32_16x16x32_bf16(a, qb0[kk], s0[kn], 0, 0, 0);
                s1[kn] = __builtin_amdgcn_mfma_f32_16x16x32_bf16(a, qb1[kk], s1[kn], 0, 0, 0);
            }
        }

        #pragma unroll
        for (int kn = 0; kn < 4; ++kn) {
            float p0[4], p1[4];
            #pragma unroll
            for (int r = 0; r < 4; ++r) {
                p0[r] = __expf(s0[kn][r]); lsum0 += p0[r];
                p1[r] = __expf(s1[kn][r]); lsum1 += p1[r];
            }
            *(uint2v*)(pt0 + l15*PT_STRIDE + kn*16 + l4*4) =
                (uint2v){pk2bf(p0[0], p0[1]), pk2bf(p0[2], p0[3])};
            *(uint2v*)(pt1 + l15*PT_STRIDE + kn*16 + l4*4) =
                (uint2v){pk2bf(p1[0], p1[1]), pk2bf(p1[2], p1[3])};
        }

        #pragma unroll
        for (int kk2 = 0; kk2 < 2; ++kk2) {
            short8 b0 = *(const short8*)(pt0 + l15*PT_STRIDE + kk2*32 + l4*8);
            short8 b1 = *(const short8*)(pt1 + l15*PT_STRIDE + kk2*32 + l4*8);
            #pragma unroll
            for (int dt = 0; dt < 7; ++dt) {
                short8 a = *(const short8*)(xt + (dt*16 + l15)*64 + (((kk2*4 + l4) ^ (l15 & 7))*8));
                o0[dt] = __builtin_amdgcn_mfma_f32_16x16x32_bf16(a, b0, o0[dt], 0, 0, 0);
                o1[dt] = __builtin_amdgcn_mfma_f32_16x16x32_bf16(a, b1, o1[dt], 0, 0, 0);
            }
        }
        __syncthreads();
    }

    float l0 = lsum0, l1 = lsum1;
    l0 += __shfl_xor(l0, 16, 64); l0 += __shfl_xor(l0, 32, 64);
    l1 += __shfl_xor(l1, 16, 64); l1 += __shfl_xor(l1, 32, 64);
    float inv0 = 1.f / l0, inv1 = 1.f / l1;

    unsigned short* Wo0 = Wb + ((long)(c*768 + q0 + wave*16 + l15))*512 + h*100 + l4*4;
    unsigned short* Wo1 = Wo0 + 64*512;
    #pragma unroll
    for (int dt = 0; dt < 7; ++dt) {
        if (dt < 6 || l4 == 0) {
            *(uint2v*)(Wo0 + dt*16) = (uint2v){pk2bf(o0[dt][0]*inv0, o0[dt][1]*inv0),
                                               pk2bf(o0[dt][2]*inv0, o0[dt][3]*inv0)};
            *(uint2v*)(Wo1 + dt*16) = (uint2v){pk2bf(o1[dt][0]*inv1, o1[dt][1]*inv1),
                                               pk2bf(o1[dt][2]*inv1, o1[dt][3]*inv1)};
        }
    }
    if (h == 0) {
        unsigned short* Wz = Wb + ((long)c*768 + q0)*512 + 500;
        for (int i = tid; i < 1536; i += 256) Wz[(long)(i/12)*512 + (i%12)] = 0;
    }
}

// ---------------- fused encoder tail: W@Ust + res + LN1 + FFN + res + LN2 (+ bf16 emit) ----
template<bool EMIT>
__global__ void __launch_bounds__(256) k_tail(const unsigned short* __restrict__ Wb,
        const unsigned short* __restrict__ UstT,
        const unsigned short* __restrict__ f1wT, const unsigned short* __restrict__ f2wT,
        const float* __restrict__ f1b, const float* __restrict__ f2b,
        const float* __restrict__ g1, const float* __restrict__ b1,
        const float* __restrict__ g2, const float* __restrict__ b2,
        float* __restrict__ x, unsigned short* __restrict__ xrow, unsigned short* __restrict__ xT) {
    __shared__ __align__(16) short zS[4][16*136];
    __shared__ __align__(16) short tS[4][16*72];
    const int tid = threadIdx.x, wave = tid >> 6, lane = tid & 63;
    const int l15 = lane & 15, l4 = lane >> 4;
    const long row = (long)blockIdx.x*64 + wave*16 + l15;
    const int cc = blockIdx.x / 12;
    const int tt = (blockIdx.x % 12)*64 + wave*16 + l15;
    short* myz = zS[wave];
    short* myt = tS[wave];

    const short* Wr = (const short*)Wb + row*512 + l4*8;
    float4v o[8];
    #pragma unroll
    for (int mt = 0; mt < 8; ++mt) o[mt] = (float4v){0,0,0,0};
    for (int ks = 0; ks < 16; ++ks) {
        short8 b = *(const short8*)(Wr + ks*32);
        #pragma unroll
        for (int mt = 0; mt < 8; ++mt) {
            short8 a = *(const short8*)((const short*)UstT + (long)(mt*16 + l15)*512 + ks*32 + l4*8);
            o[mt] = __builtin_amdgcn_mfma_f32_16x16x32_bf16(a, b, o[mt], 0, 0, 0);
        }
    }

    float zv[7][4];
    float sum = 0.f;
    #pragma unroll
    for (int mt = 0; mt < 7; ++mt) {
        int f0 = mt*16 + l4*4;
        float4 xv = {0,0,0,0};
        if (f0 < 100) xv = *(const float4*)(x + row*100 + f0);
        #pragma unroll
        for (int r = 0; r < 4; ++r) {
            float z = 0.f;
            if (f0 < 100) { z = o[mt][r] + ((const float*)&xv)[r]; sum += z; }
            zv[mt][r] = z;
        }
    }
    sum += __shfl_xor(sum, 16, 64); sum += __shfl_xor(sum, 32, 64);
    float mean = sum * 0.01f;
    float vs = 0.f;
    #pragma unroll
    for (int mt = 0; mt < 7; ++mt) {
        if (mt*16 + l4*4 < 100) {
            #pragma unroll
            for (int r = 0; r < 4; ++r) { float d = zv[mt][r] - mean; vs += d*d; }
        }
    }
    vs += __shfl_xor(vs, 16, 64); vs += __shfl_xor(vs, 32, 64);
    float inv = rsqrtf(vs * 0.01f + 1e-5f);
    float x1r[7][4];
    #pragma unroll
    for (int mt = 0; mt < 7; ++mt) {
        int f0 = mt*16 + l4*4;
        float4 gv = {0,0,0,0}, bv = {0,0,0,0};
        if (f0 < 100) { gv = *(const float4*)(g1 + f0); bv = *(const float4*)(b1 + f0); }
        #pragma unroll
        for (int r = 0; r < 4; ++r)
            x1r[mt][r] = (f0 < 100) ? (zv[mt][r] - mean) * inv * ((const float*)&gv)[r] + ((const float*)&bv)[r] : 0.f;
    }

    #pragma unroll
    for (int mt = 0; mt < 8; ++mt) {
        float v0 = (mt < 7) ? x1r[mt][0] : 0.f, v1 = (mt < 7) ? x1r[mt][1] : 0.f;
        float v2 = (mt < 7) ? x1r[mt][2] : 0.f, v3 = (mt < 7) ? x1r[mt][3] : 0.f;
        *(uint2v*)(myz + l15*136 + mt*16 + l4*4) = (uint2v){pk2bf(v0, v1), pk2bf(v2, v3)};
    }

    float4v t2[4];
    #pragma unroll
    for (int m2t = 0; m2t < 4; ++m2t) t2[m2t] = (float4v){0,0,0,0};
    #pragma unroll
    for (int ks = 0; ks < 4; ++ks) {
        short8 b = *(const short8*)(myz + l15*136 + ks*32 + l4*8);
        #pragma unroll
        for (int m2t = 0; m2t < 4; ++m2t) {
            short8 a = *(const short8*)((const short*)f1wT + (m2t*16 + l15)*128 + ks*32 + l4*8);
            t2[m2t] = __builtin_amdgcn_mfma_f32_16x16x32_bf16(a, b, t2[m2t], 0, 0, 0);
        }
    }
    #pragma unroll
    for (int m2t = 0; m2t < 4; ++m2t) {
        int m20 = m2t*16 + l4*4;
        float4 bv = *(const float4*)(f1b + m20);
        float v0 = fmaxf(t2[m2t][0] + ((const float*)&bv)[0], 0.f);
        float v1 = fmaxf(t2[m2t][1] + ((const float*)&bv)[1], 0.f);
        float v2 = fmaxf(t2[m2t][2] + ((const float*)&bv)[2], 0.f);
        float v3 = fmaxf(t2[m2t][3] + ((const float*)&bv)[3], 0.f);
        *(uint2v*)(myt + l15*72 + m20) = (uint2v){pk2bf(v0, v1), pk2bf(v2, v3)};
    }

    float4v o3[7];
    #pragma unroll
    for (int m3t = 0; m3t < 7; ++m3t) o3[m3t] = (float4v){0,0,0,0};
    #pragma unroll
    for (int ks2 = 0; ks2 < 2; ++ks2) {
        short8 b = *(const short8*)(myt + l15*72 + ks2*32 + l4*8);
        #pragma unroll
        for (int m3t = 0; m3t < 7; ++m3t) {
            short8 a = *(const short8*)((const short*)f2wT + (m3t*16 + l15)*64 + ks2*32 + l4*8);
            o3[m3t] = __builtin_amdgcn_mfma_f32_16x16x32_bf16(a, b, o3[m3t], 0, 0, 0);
        }
    }

    float z2[7][4];
    float sum2 = 0.f;
    #pragma unroll
    for (int m3t = 0; m3t < 7; ++m3t) {
        int f0 = m3t*16 + l4*4;
        float4 bv = {0,0,0,0};
        if (f0 < 100) bv = *(const float4*)(f2b + f0);
        #pragma unroll
        for (int r = 0; r < 4; ++r) {
            float z = 0.f;
            if (f0 < 100) { z = o3[m3t][r] + ((const float*)&bv)[r] + x1r[m3t][r]; sum2 += z; }
            z2[m3t][r] = z;
        }
    }
    sum2 += __shfl_xor(sum2, 16, 64); sum2 += __shfl_xor(sum2, 32, 64);
    float mean2 = sum2 * 0.01f;
    float vs2 = 0.f;
    #pragma unroll
    for (int m3t = 0; m3t < 7; ++m3t) {
        if (m3t*16 + l4*4 < 100) {
            #pragma unroll
            for (int r = 0; r < 4; ++r) { float d = z2[m3t][r] - mean2; vs2 += d*d; }
        }
    }
    vs2 += __shfl_xor(vs2, 16, 64); vs2 += __shfl_xor(vs2, 32, 64);
    float inv2 = rsqrtf(vs2 * 0.01f + 1e-5f);

    unsigned short* xTc = EMIT ? (xT + (long)cc*98304 + tt) : nullptr;
    #pragma unroll
    for (int m3t = 0; m3t < 7; ++m3t) {
        int f0 = m3t*16 + l4*4;
        if (f0 < 100) {
            float4 gv = *(const float4*)(g2 + f0);
            float4 bv = *(const float4*)(b2 + f0);
            float y[4];
            #pragma unroll
            for (int r = 0; r < 4; ++r)
                y[r] = (z2[m3t][r] - mean2) * inv2 * ((const float*)&gv)[r] + ((const float*)&bv)[r];
            *(float4*)(x + row*100 + f0) = (float4){y[0], y[1], y[2], y[3]};
            if (EMIT) {
                *(uint2v*)(xrow + row*128 + f0) = (uint2v){pk2bf(y[0], y[1]), pk2bf(y[2], y[3])};
                #pragma unroll
                for (int r = 0; r < 4; ++r)
                    xTc[(long)(f0 + r)*768] = f2bf(y[r]);
            }
        } else if (EMIT) {
            *(uint2v*)(xrow + row*128 + f0) = (uint2v){0u, 0u};
            #pragma unroll
            for (int r = 0; r < 4; ++r)
                if (f0 + r < 112) xTc[(long)(f0 + r)*768] = 0;
        }
    }
    if (EMIT) *(uint2v*)(xrow + row*128 + 112 + l4*4) = (uint2v){0u, 0u};
}

// ---------------- autoregressive predictor (composed linear map) ----------------
__global__ void __launch_bounds__(256) k_pred2(const float* __restrict__ xf,
        const float* __restrict__ Mp, const float* __restrict__ c0v,
        float* __restrict__ out) {
    int c = blockIdx.x, tid = threadIdx.x;
    __shared__ float Ml[10000];
    __shared__ float carry[100];
    for (int i = tid; i < 10000; i += 256) Ml[i] = Mp[i];
    if (tid < 100) carry[tid] = xf[((long)c*768 + 767)*100 + tid];
    __syncthreads();
    for (int s = 0; s < 10; ++s) {
        float pv = 0.f;
        if (tid < 100) {
            pv = c0v[tid];
            for (int d = 0; d < 100; ++d) pv += carry[d] * Ml[d*100 + tid];
            out[((long)c*10 + s)*100 + tid] = pv;
        }
        __syncthreads();
        if (tid < 100) carry[tid] = pv;
        __syncthreads();
    }
}

extern "C" void kernel_launch(void* const* d_in, const int* in_sizes, int n_in,
                              void* d_out, int out_size, void* d_ws, size_t ws_size,
                              hipStream_t stream) {
    const float* X    = (const float*)d_in[0];
    const float* A    = (const float*)d_in[1];
    const float* gw1  = (const float*)d_in[2];
    const float* gb1  = (const float*)d_in[3];
    const float* gw2  = (const float*)d_in[4];
    const float* gb2  = (const float*)d_in[5];
    const float* wq   = (const float*)d_in[6];
    const float* wk   = (const float*)d_in[7];
    const float* wv   = (const float*)d_in[8];
    const float* wm   = (const float*)d_in[9];
    const float* f1w  = (const float*)d_in[10];
    const float* f1b  = (const float*)d_in[11];
    const float* f2w  = (const float*)d_in[12];
    const float* f2b  = (const float*)d_in[13];
    const float* ln1g = (const float*)d_in[14];
    const float* ln1b = (const float*)d_in[15];
    const float* ln2g = (const float*)d_in[16];
    const float* ln2b = (const float*)d_in[17];
    const float* l1w  = (const float*)d_in[18];
    const float* l1b  = (const float*)d_in[19];
    const float* l2w  = (const float*)d_in[20];
    const float* l2b  = (const float*)d_in[21];
    (void)in_sizes; (void)n_in; (void)out_size; (void)ws_size;

    float* ws   = (float*)d_ws;
    float* adjh = ws + OFF_ADJ;
    float* x0   = ws + OFF_X0;
    float* x1   = ws + OFF_X1;
    float* hid  = ws + OFF_HID;
    unsigned short* xrow = (unsigned short*)(ws + OFF_XROW);
    unsigned short* xTb  = (unsigned short*)(ws + OFF_XT);
    unsigned short* Wbf  = (unsigned short*)(ws + OFF_WBF);
    unsigned short* MhT  = (unsigned short*)(ws + OFF_MHT);
    unsigned short* UstT = (unsigned short*)(ws + OFF_USTT);
    float* Mp   = ws + OFF_MP;
    float* c0v  = ws + OFF_C0;
    unsigned short* f1wT = (unsigned short*)(ws + OFF_F1WT);
    unsigned short* f2wT = (unsigned short*)(ws + OFF_F2WT);
    float* out  = (float*)d_out;

    k_mu2<<<501, 256, 0, stream>>>(wq, wk, wv, wm, l1w, l1b, l2w, l2b, f1w, f2w, A,
                                   MhT, UstT, Mp, c0v, f1wT, f2wT, adjh);

    // GCN
    k_spmm<<<300, 256, 0, stream>>>(adjh, X, x1, 76800);
    k_gemm<8, true, true><<<768, 256, 0, stream>>>(x1, gw1, gb1, hid, ROWS, 60, 100);
    k_spmm<<<180, 256, 0, stream>>>(adjh, hid, x1, 46080);
    k_gemm<13, false, true><<<768, 256, 0, stream>>>(x1, gw2, gb2, x0, ROWS, 100, 60);

    // encoder layers: attn + fused tail
    k_prep<<<dim3(12,32), 256, 0, stream>>>(x0, xrow, xTb);
    for (int l = 0; l < 3; ++l) {
        k_attn6<<<dim3(6,5,32), 256, 0, stream>>>(xrow, xTb, MhT + (long)l*81920, Wbf);
        if (l < 2)
            k_tail<true><<<384, 256, 0, stream>>>(Wbf, UstT + (long)l*65536,
                f1wT + (long)l*8192, f2wT + (long)l*7168, f1b + l*64, f2b + l*100,
                ln1g + l*100, ln1b + l*100, ln2g + l*100, ln2b + l*100, x0, xrow, xTb);
        else
            k_tail<false><<<384, 256, 0, stream>>>(Wbf, UstT + (long)l*65536,
                f1wT + (long)l*8192, f2wT + (long)l*7168, f1b + l*64, f2b + l*100,
                ln1g + l*100, ln1b + l*100, ln2g + l*100, ln2b + l*100, x0, xrow, xTb);
    }

    k_pred2<<<32, 256, 0, stream>>>(x0, Mp, c0v, out);
}

// Round 14
// 545.224 us; speedup vs baseline: 1.4036x; 1.0843x over previous
//
#include <hip/hip_runtime.h>

// GTA model: GCN(2-hop) -> 3x transformer encoder -> 10-step AR predictor.
// R13: GCN moved to MFMA via associativity: (adjh@X)@w1 = adjh@(X@w1), so
// weight-GEMMs run as barrier-free MFMA kernels (k_gw1/k_gw2) and the chart-
// mixing spmms operate on bf16 60/128-wide tensors (k_spmmg/k_spmmx).
// Attention = R9 k_attn6 (87us plateau, barrier-structural). Tail fused (R9).

#define ROWS 24576   // C*T = 32*768

// workspace offsets (floats)
#define OFF_ADJ   0L
#define OFF_X0    1024L
#define OFF_X1    (OFF_X0 + 2457600L)
#define OFF_XROW  (OFF_X1 + 3932160L)        // 24576*128 bf16 = 1572864 floats
#define OFF_XT    (OFF_XROW + 1572864L)
#define OFF_WBF   (OFF_XT + 1572864L)        // 24576*512 bf16 = 6291456 floats
#define OFF_MHT   (OFF_WBF + 6291456L)       // 15*128*128 bf16 = 122880 floats
#define OFF_USTT  (OFF_MHT + 122880L)        // 3*128*512 bf16 = 98304 floats
#define OFF_MP    (OFF_USTT + 98304L)        // 100*100 fp32
#define OFF_C0    (OFF_MP + 10000L)          // 100 fp32 (pad to 128)
#define OFF_F1WT  (OFF_C0 + 128L)            // 3*64*128 bf16 = 12288 floats
#define OFF_F2WT  (OFF_F1WT + 12288L)        // 3*112*64 bf16 = 10752 floats
#define OFF_GW1T  (OFF_F2WT + 10752L)        // 64*128 bf16 = 4096 floats
#define OFF_GW2T  (OFF_GW1T + 4096L)         // 112*64 bf16 = 3584 floats
// GCN scratch inside OFF_X1 region (3932160 floats):
//   g   bf16 24576*64  = 786432 floats @ OFF_X1
//   hid bf16 24576*64  = 786432 floats @ OFF_X1 + 786432
//   h2  bf16 24576*128 = 1572864 floats @ OFF_X1 + 1572864

typedef __attribute__((ext_vector_type(8))) short short8;
typedef __attribute__((ext_vector_type(4))) float float4v;
typedef __attribute__((ext_vector_type(2))) unsigned int uint2v;

__device__ inline unsigned short f2bf(float f) {
    unsigned u = __builtin_bit_cast(unsigned, f);
    return (unsigned short)((u + 0x7fffu + ((u >> 16) & 1u)) >> 16);
}
__device__ inline unsigned pk2bf(float lo, float hi) {
    return (unsigned)f2bf(lo) | ((unsigned)f2bf(hi) << 16);
}
__device__ inline float bf2f(unsigned short v) {
    return __builtin_bit_cast(float, ((unsigned)v) << 16);
}
// async global->LDS DMA, 16B per lane; LDS dest = wave-uniform base + lane*16
__device__ inline void gload16(const short* g, short* l) {
    __builtin_amdgcn_global_load_lds((const __attribute__((address_space(1))) void*)g,
                                     (__attribute__((address_space(3))) void*)l, 16, 0, 0);
}

// ---------------- precompute: MhT, UstT, f1wT, f2wT, gw1T, gw2T (bf16 padded), Mpred, c0, adjh ----
__global__ void __launch_bounds__(256) k_mu2(const float* __restrict__ wq, const float* __restrict__ wk,
                                             const float* __restrict__ wv, const float* __restrict__ wm,
                                             const float* __restrict__ l1w, const float* __restrict__ l1b,
                                             const float* __restrict__ l2w, const float* __restrict__ l2b,
                                             const float* __restrict__ f1w, const float* __restrict__ f2w,
                                             const float* __restrict__ A,
                                             const float* __restrict__ gw1, const float* __restrict__ gw2,
                                             unsigned short* __restrict__ MhT, unsigned short* __restrict__ UstT,
                                             float* __restrict__ Mp, float* __restrict__ c0v,
                                             unsigned short* __restrict__ f1wT, unsigned short* __restrict__ f2wT,
                                             float* __restrict__ adjh,
                                             unsigned short* __restrict__ gw1T, unsigned short* __restrict__ gw2T) {
    int bi = blockIdx.x, tid = threadIdx.x;
    if (bi < 480) {
        int mat = bi >> 4, sub = bi & 15;
        int mode = mat / 15, idx = mat % 15, l = idx / 5, h = idx % 5;
        const float* Asrc = (mode == 0 ? wq : wv) + (l*5 + h)*10000;
        const float* Bsrc = (mode == 0) ? (wk + (l*5 + h)*10000) : (wm + l*50000 + h*10000);
        int oend = sub*625 + 625;
        for (int o = sub*625 + tid; o < oend; o += 256) {
            int r = o / 100, cix = o - (o/100)*100;
            const float* arow = Asrc + r*100;
            float acc = 0.f;
            if (mode == 0) {
                const float* brow = Bsrc + cix*100;
                for (int e = 0; e < 100; ++e) acc += arow[e] * brow[e];
                MhT[(long)(l*5 + h)*16384 + cix*128 + r] = f2bf(acc * 0.1f);
            } else {
                for (int e = 0; e < 100; ++e) acc += arow[e] * Bsrc[e*100 + cix];
                UstT[(long)l*65536 + (long)cix*512 + h*100 + r] = f2bf(acc);
            }
        }
        if (sub == 0) {   // zero padding
            if (mode == 0) {
                unsigned short* M0 = MhT + (long)(l*5 + h)*16384;
                for (int i = tid; i < 28*128; i += 256) M0[(100 + i/128)*128 + (i%128)] = 0;
                for (int i = tid; i < 100*28; i += 256) M0[(i/28)*128 + 100 + (i%28)] = 0;
            } else if (h == 4) {
                unsigned short* U0 = UstT + (long)l*65536;
                for (int i = tid; i < 28*512; i += 256) U0[(long)(100 + i/512)*512 + (i%512)] = 0;
                for (int i = tid; i < 100*12; i += 256) U0[(long)(i/12)*512 + 500 + (i%12)] = 0;
            }
        }
    } else if (bi < 496) {
        int sub = bi - 480;
        int oend = sub*625 + 625;
        for (int o = sub*625 + tid; o < oend; o += 256) {
            int r = o / 100, cix = o - (o/100)*100;
            const float* arow = l1w + r*200;
            float acc = 0.f;
            for (int e = 0; e < 200; ++e) acc += arow[e] * l2w[e*100 + cix];
            Mp[r*100 + cix] = acc;
        }
    } else if (bi == 496) {
        if (tid < 100) {
            float acc = l2b[tid];
            for (int e = 0; e < 200; ++e) acc += l1b[e] * l2w[e*100 + tid];
            c0v[tid] = acc;
        }
    } else if (bi < 500) {
        int l = bi - 497;   // per-layer FFN weight transposes
        unsigned short* F1 = f1wT + (long)l*8192;
        for (int i = tid; i < 8192; i += 256) {
            int o = i >> 7, k = i & 127;
            F1[i] = (k < 100) ? f2bf(f1w[l*6400 + k*64 + o]) : (unsigned short)0;
        }
        unsigned short* F2 = f2wT + (long)l*7168;
        for (int i = tid; i < 7168; i += 256) {
            int o2 = i >> 6, k2 = i & 63;
            F2[i] = (o2 < 100) ? f2bf(f2w[l*6400 + k2*100 + o2]) : (unsigned short)0;
        }
    } else if (bi == 500) {
        // adjacency normalization
        __shared__ float adj[1024];
        __shared__ float rs[32];
        for (int i = tid; i < 1024; i += 256) {
            int r = i >> 5, j = i & 31;
            adj[i] = A[i] + (r == j ? 1.f : 0.f);
        }
        __syncthreads();
        if (tid < 32) {
            float s = 0.f;
            #pragma unroll
            for (int jj = 0; jj < 32; ++jj) s += adj[tid*32 + jj];
            rs[tid] = s;
        }
        __syncthreads();
        for (int i = tid; i < 1024; i += 256) adjh[i] = adj[i] / rs[i >> 5];
    } else {
        // GCN weight transposes: gw1T[o:64][k:128], gw2T[o:112][k:64]
        for (int i = tid; i < 8192; i += 256) {
            int o = i >> 7, k = i & 127;
            gw1T[i] = (o < 60 && k < 100) ? f2bf(gw1[k*60 + o]) : (unsigned short)0;
        }
        for (int i = tid; i < 7168; i += 256) {
            int o = i >> 6, k = i & 63;
            gw2T[i] = (o < 100 && k < 60) ? f2bf(gw2[k*100 + o]) : (unsigned short)0;
        }
    }
}

// ---------------- GCN gemm1: g[row][64] bf16 = X @ w1 (transposed-domain MFMA) ----------------
__global__ void __launch_bounds__(256) k_gw1(const float* __restrict__ X,
                                             const unsigned short* __restrict__ gw1T,
                                             unsigned short* __restrict__ g) {
    const int tid = threadIdx.x, wave = tid >> 6, lane = tid & 63;
    const int l15 = lane & 15, l4 = lane >> 4;
    const long row = (long)blockIdx.x*64 + wave*16 + l15;
    const float* xrp = X + row*100;
    float4v acc[4];
    #pragma unroll
    for (int mt = 0; mt < 4; ++mt) acc[mt] = (float4v){0,0,0,0};
    #pragma unroll
    for (int ks = 0; ks < 4; ++ks) {
        short8 b;
        #pragma unroll
        for (int e = 0; e < 8; ++e) {
            int k = ks*32 + l4*8 + e;
            b[e] = (k < 100) ? (short)f2bf(xrp[k]) : (short)0;
        }
        #pragma unroll
        for (int mt = 0; mt < 4; ++mt) {
            short8 a = *(const short8*)((const short*)gw1T + (mt*16 + l15)*128 + ks*32 + l4*8);
            acc[mt] = __builtin_amdgcn_mfma_f32_16x16x32_bf16(a, b, acc[mt], 0, 0, 0);
        }
    }
    #pragma unroll
    for (int mt = 0; mt < 4; ++mt) {
        int o0 = mt*16 + l4*4;
        *(uint2v*)(g + row*64 + o0) =
            (uint2v){pk2bf(acc[mt][0], acc[mt][1]), pk2bf(acc[mt][2], acc[mt][3])};
    }
}

// ---------------- GCN spmm1: hid[row][64] bf16 = relu(adjh @ g + b1) ----------------
__global__ void __launch_bounds__(256) k_spmmg(const float* __restrict__ adjh,
                                               const unsigned short* __restrict__ g,
                                               const float* __restrict__ b1,
                                               unsigned short* __restrict__ hid) {
    __shared__ float adj[1024];
    int tid = threadIdx.x;
    for (int i = tid; i < 1024; i += 256) adj[i] = adjh[i];
    __syncthreads();
    long p = (long)blockIdx.x*256 + tid;     // p = t*64 + o, in [0, 49152)
    int o = (int)(p & 63);
    float acc[32];
    #pragma unroll
    for (int i = 0; i < 32; ++i) acc[i] = 0.f;
    for (int j = 0; j < 32; ++j) {
        float xv = bf2f(g[(long)j*49152 + p]);
        #pragma unroll
        for (int i = 0; i < 32; ++i) acc[i] += adj[i*32 + j] * xv;
    }
    float bias = (o < 60) ? b1[o] : 0.f;
    #pragma unroll
    for (int i = 0; i < 32; ++i) hid[(long)i*49152 + p] = f2bf(fmaxf(acc[i] + bias, 0.f));
}

// ---------------- GCN gemm2: h2[row][128] bf16 = hid @ w2 ----------------
__global__ void __launch_bounds__(256) k_gw2(const unsigned short* __restrict__ hid,
                                             const unsigned short* __restrict__ gw2T,
                                             unsigned short* __restrict__ h2) {
    const int tid = threadIdx.x, wave = tid >> 6, lane = tid & 63;
    const int l15 = lane & 15, l4 = lane >> 4;
    const long row = (long)blockIdx.x*64 + wave*16 + l15;
    float4v acc[7];
    #pragma unroll
    for (int mt = 0; mt < 7; ++mt) acc[mt] = (float4v){0,0,0,0};
    #pragma unroll
    for (int ks = 0; ks < 2; ++ks) {
        short8 b = *(const short8*)((const short*)hid + row*64 + ks*32 + l4*8);
        #pragma unroll
        for (int mt = 0; mt < 7; ++mt) {
            short8 a = *(const short8*)((const short*)gw2T + (mt*16 + l15)*64 + ks*32 + l4*8);
            acc[mt] = __builtin_amdgcn_mfma_f32_16x16x32_bf16(a, b, acc[mt], 0, 0, 0);
        }
    }
    #pragma unroll
    for (int mt = 0; mt < 7; ++mt) {
        int o0 = mt*16 + l4*4;
        *(uint2v*)(h2 + row*128 + o0) =
            (uint2v){pk2bf(acc[mt][0], acc[mt][1]), pk2bf(acc[mt][2], acc[mt][3])};
    }
    *(uint2v*)(h2 + row*128 + 112 + l4*4) = (uint2v){0u, 0u};
}

// ---------------- GCN spmm2: x0[row][100] fp32 = adjh @ h2 + b2 ----------------
__global__ void __launch_bounds__(256) k_spmmx(const float* __restrict__ adjh,
                                               const unsigned short* __restrict__ h2,
                                               const float* __restrict__ b2,
                                               float* __restrict__ x0) {
    __shared__ float adj[1024];
    int tid = threadIdx.x;
    for (int i = tid; i < 1024; i += 256) adj[i] = adjh[i];
    __syncthreads();
    long p = (long)blockIdx.x*256 + tid;     // p = t*128 + o, in [0, 98304)
    int o = (int)(p & 127);
    int t = (int)(p >> 7);
    float acc[32];
    #pragma unroll
    for (int i = 0; i < 32; ++i) acc[i] = 0.f;
    for (int j = 0; j < 32; ++j) {
        float xv = bf2f(h2[(long)j*98304 + p]);
        #pragma unroll
        for (int i = 0; i < 32; ++i) acc[i] += adj[i*32 + j] * xv;
    }
    if (o < 100) {
        float bias = b2[o];
        #pragma unroll
        for (int i = 0; i < 32; ++i) x0[((long)i*768 + t)*100 + o] = acc[i] + bias;
    }
}

// ---------------- x fp32 -> bf16 row-major [c][t][128] and transposed [c][128][t] ----------------
__global__ void __launch_bounds__(256) k_prep(const float* __restrict__ x, unsigned short* __restrict__ xrow,
                                              unsigned short* __restrict__ xT) {
    int c = blockIdx.y, t0 = blockIdx.x * 64;
    int tid = threadIdx.x;
    __shared__ float xs[64][101];
    const float* xp = x + ((long)c*768 + t0) * 100;
    for (int i = tid; i < 6400; i += 256) {
        int r = i / 100, d = i - r*100;
        xs[r][d] = xp[i];
    }
    __syncthreads();
    unsigned short* xro = xrow + ((long)c*768 + t0) * 128;
    for (int i = tid; i < 8192; i += 256) {
        int r = i >> 7, d = i & 127;
        xro[i] = (d < 100) ? f2bf(xs[r][d]) : (unsigned short)0;
    }
    unsigned short* xto = xT + (long)c*128*768 + t0;
    for (int i = tid; i < 8192; i += 256) {
        int d = i >> 6, t = i & 63;
        xto[(long)d*768 + t] = (d < 100) ? f2bf(xs[t][d]) : (unsigned short)0;
    }
}

// ---------------- fused Q-proj + flash attention, DMA-staged swizzled LDS (R9) ----------------
#define QP_STRIDE 136
#define PT_STRIDE 72

__global__ void __launch_bounds__(256) k_attn6(const unsigned short* __restrict__ xrow,
                                               const unsigned short* __restrict__ xT,
                                               const unsigned short* __restrict__ MhT,
                                               unsigned short* __restrict__ Wb) {
    __shared__ __align__(16) short xr[64 * 128];
    __shared__ __align__(16) short xt[112 * 64];
    __shared__ __align__(16) short scratch[4][2304];
    const int tid = threadIdx.x;
    const int wave = tid >> 6, lane = tid & 63;
    const int l15 = lane & 15, l4 = lane >> 4;
    const int c = blockIdx.z, h = blockIdx.y, q0 = blockIdx.x * 128;
    short* myq = scratch[wave];
    short* pt0 = scratch[wave];
    short* pt1 = scratch[wave] + 1152;

    short8 qb0[4], qb1[4];
    {
        const short* xq = (const short*)xrow + ((long)c*768 + q0 + wave*16 + l15)*128 + l4*8;
        short8 bq0[4], bq1[4];
        #pragma unroll
        for (int kk = 0; kk < 4; ++kk) {
            bq0[kk] = *(const short8*)(xq + kk*32);
            bq1[kk] = *(const short8*)(xq + 64*128 + kk*32);
        }
        const short* Mb = (const short*)MhT + (long)h*16384 + l15*128 + l4*8;
        float4v qc0[8], qc1[8];
        #pragma unroll
        for (int mt = 0; mt < 8; ++mt) { qc0[mt] = (float4v){0,0,0,0}; qc1[mt] = (float4v){0,0,0,0}; }
        #pragma unroll
        for (int mt = 0; mt < 8; ++mt) {
            #pragma unroll
            for (int kk = 0; kk < 4; ++kk) {
                short8 a = *(const short8*)(Mb + (mt*16)*128 + kk*32);
                qc0[mt] = __builtin_amdgcn_mfma_f32_16x16x32_bf16(a, bq0[kk], qc0[mt], 0, 0, 0);
                qc1[mt] = __builtin_amdgcn_mfma_f32_16x16x32_bf16(a, bq1[kk], qc1[mt], 0, 0, 0);
            }
        }
        #pragma unroll
        for (int mt = 0; mt < 8; ++mt)
            *(uint2v*)(myq + l15*QP_STRIDE + mt*16 + l4*4) =
                (uint2v){pk2bf(qc0[mt][0], qc0[mt][1]), pk2bf(qc0[mt][2], qc0[mt][3])};
        #pragma unroll
        for (int kk = 0; kk < 4; ++kk) qb0[kk] = *(const short8*)(myq + l15*QP_STRIDE + kk*32 + l4*8);
        #pragma unroll
        for (int mt = 0; mt < 8; ++mt)
            *(uint2v*)(myq + l15*QP_STRIDE + mt*16 + l4*4) =
                (uint2v){pk2bf(qc1[mt][0], qc1[mt][1]), pk2bf(qc1[mt][2], qc1[mt][3])};
        #pragma unroll
        for (int kk = 0; kk < 4; ++kk) qb1[kk] = *(const short8*)(myq + l15*QP_STRIDE + kk*32 + l4*8);
    }

    float4v o0[7], o1[7];
    #pragma unroll
    for (int n = 0; n < 7; ++n) { o0[n] = (float4v){0,0,0,0}; o1[n] = (float4v){0,0,0,0}; }
    float lsum0 = 0.f, lsum1 = 0.f;

    const short* xrg = (const short*)xrow + (long)c*768*128;
    const short* xtg = (const short*)xT + (long)c*128*768;
    const int rl4 = lane >> 4, cp16 = lane & 15;
    const int rl8 = lane >> 3, cp8 = lane & 7;
    const int njt = (wave == 3) ? 2 : 4;

    for (int kt = 0; kt < 12; ++kt) {
        const int key0 = kt * 64;
        #pragma unroll
        for (int j = 0; j < 4; ++j) {
            int row = wave*16 + j*4 + rl4;
            int lc = cp16 ^ (row & 7);
            gload16(xrg + (long)(key0 + row)*128 + lc*8, xr + (wave*16 + j*4)*128);
        }
        for (int j = 0; j < njt; ++j) {
            int row = wave*32 + j*8 + rl8;
            int lc = cp8 ^ (row & 7);
            gload16(xtg + (long)row*768 + key0 + lc*8, xt + (wave*32 + j*8)*64);
        }
        __syncthreads();

        float4v s0[4], s1[4];
        #pragma unroll
        for (int kn = 0; kn < 4; ++kn) { s0[kn] = (float4v){0,0,0,0}; s1[kn] = (float4v){0,0,0,0}; }
        #pragma unroll
        for (int kn = 0; kn < 4; ++kn) {
            #pragma unroll
            for (int kk = 0; kk < 4; ++kk) {
                short8 a = *(const short8*)(xr + (kn*16 + l15)*128 + (((kk*4 + l4) ^ (l15 & 7))*8));
                s0[kn] = __builtin_amdgcn_mfma_f32_16x16x32_bf16(a, qb0[kk], s0[kn], 0, 0, 0);
                s1[kn] = __builtin_amdgcn_mfma_f32_16x16x32_bf16(a, qb1[kk], s1[kn], 0, 0, 0);
            }
        }

        #pragma unroll
        for (int kn = 0; kn < 4; ++kn) {
            float p0[4], p1[4];
            #pragma unroll
            for (int r = 0; r < 4; ++r) {
                p0[r] = __expf(s0[kn][r]); lsum0 += p0[r];
                p1[r] = __expf(s1[kn][r]); lsum1 += p1[r];
            }
            *(uint2v*)(pt0 + l15*PT_STRIDE + kn*16 + l4*4) =
                (uint2v){pk2bf(p0[0], p0[1]), pk2bf(p0[2], p0[3])};
            *(uint2v*)(pt1 + l15*PT_STRIDE + kn*16 + l4*4) =
                (uint2v){pk2bf(p1[0], p1[1]), pk2bf(p1[2], p1[3])};
        }

        #pragma unroll
        for (int kk2 = 0; kk2 < 2; ++kk2) {
            short8 b0 = *(const short8*)(pt0 + l15*PT_STRIDE + kk2*32 + l4*8);
            short8 b1 = *(const short8*)(pt1 + l15*PT_STRIDE + kk2*32 + l4*8);
            #pragma unroll
            for (int dt = 0; dt < 7; ++dt) {
                short8 a = *(const short8*)(xt + (dt*16 + l15)*64 + (((kk2*4 + l4) ^ (l15 & 7))*8));
                o0[dt] = __builtin_amdgcn_mfma_f32_16x16x32_bf16(a, b0, o0[dt], 0, 0, 0);
                o1[dt] = __builtin_amdgcn_mfma_f32_16x16x32_bf16(a, b1, o1[dt], 0, 0, 0);
            }
        }
        __syncthreads();
    }

    float l0 = lsum0, l1 = lsum1;
    l0 += __shfl_xor(l0, 16, 64); l0 += __shfl_xor(l0, 32, 64);
    l1 += __shfl_xor(l1, 16, 64); l1 += __shfl_xor(l1, 32, 64);
    float inv0 = 1.f / l0, inv1 = 1.f / l1;

    unsigned short* Wo0 = Wb + ((long)(c*768 + q0 + wave*16 + l15))*512 + h*100 + l4*4;
    unsigned short* Wo1 = Wo0 + 64*512;
    #pragma unroll
    for (int dt = 0; dt < 7; ++dt) {
        if (dt < 6 || l4 == 0) {
            *(uint2v*)(Wo0 + dt*16) = (uint2v){pk2bf(o0[dt][0]*inv0, o0[dt][1]*inv0),
                                               pk2bf(o0[dt][2]*inv0, o0[dt][3]*inv0)};
            *(uint2v*)(Wo1 + dt*16) = (uint2v){pk2bf(o1[dt][0]*inv1, o1[dt][1]*inv1),
                                               pk2bf(o1[dt][2]*inv1, o1[dt][3]*inv1)};
        }
    }
    if (h == 0) {
        unsigned short* Wz = Wb + ((long)c*768 + q0)*512 + 500;
        for (int i = tid; i < 1536; i += 256) Wz[(long)(i/12)*512 + (i%12)] = 0;
    }
}

// ---------------- fused encoder tail: W@Ust + res + LN1 + FFN + res + LN2 (+ bf16 emit) ----
template<bool EMIT>
__global__ void __launch_bounds__(256) k_tail(const unsigned short* __restrict__ Wb,
        const unsigned short* __restrict__ UstT,
        const unsigned short* __restrict__ f1wT, const unsigned short* __restrict__ f2wT,
        const float* __restrict__ f1b, const float* __restrict__ f2b,
        const float* __restrict__ g1, const float* __restrict__ b1,
        const float* __restrict__ g2, const float* __restrict__ b2,
        float* __restrict__ x, unsigned short* __restrict__ xrow, unsigned short* __restrict__ xT) {
    __shared__ __align__(16) short zS[4][16*136];
    __shared__ __align__(16) short tS[4][16*72];
    const int tid = threadIdx.x, wave = tid >> 6, lane = tid & 63;
    const int l15 = lane & 15, l4 = lane >> 4;
    const long row = (long)blockIdx.x*64 + wave*16 + l15;
    const int cc = blockIdx.x / 12;
    const int tt = (blockIdx.x % 12)*64 + wave*16 + l15;
    short* myz = zS[wave];
    short* myt = tS[wave];

    const short* Wr = (const short*)Wb + row*512 + l4*8;
    float4v o[8];
    #pragma unroll
    for (int mt = 0; mt < 8; ++mt) o[mt] = (float4v){0,0,0,0};
    for (int ks = 0; ks < 16; ++ks) {
        short8 b = *(const short8*)(Wr + ks*32);
        #pragma unroll
        for (int mt = 0; mt < 8; ++mt) {
            short8 a = *(const short8*)((const short*)UstT + (long)(mt*16 + l15)*512 + ks*32 + l4*8);
            o[mt] = __builtin_amdgcn_mfma_f32_16x16x32_bf16(a, b, o[mt], 0, 0, 0);
        }
    }

    float zv[7][4];
    float sum = 0.f;
    #pragma unroll
    for (int mt = 0; mt < 7; ++mt) {
        int f0 = mt*16 + l4*4;
        float4 xv = {0,0,0,0};
        if (f0 < 100) xv = *(const float4*)(x + row*100 + f0);
        #pragma unroll
        for (int r = 0; r < 4; ++r) {
            float z = 0.f;
            if (f0 < 100) { z = o[mt][r] + ((const float*)&xv)[r]; sum += z; }
            zv[mt][r] = z;
        }
    }
    sum += __shfl_xor(sum, 16, 64); sum += __shfl_xor(sum, 32, 64);
    float mean = sum * 0.01f;
    float vs = 0.f;
    #pragma unroll
    for (int mt = 0; mt < 7; ++mt) {
        if (mt*16 + l4*4 < 100) {
            #pragma unroll
            for (int r = 0; r < 4; ++r) { float d = zv[mt][r] - mean; vs += d*d; }
        }
    }
    vs += __shfl_xor(vs, 16, 64); vs += __shfl_xor(vs, 32, 64);
    float inv = rsqrtf(vs * 0.01f + 1e-5f);
    float x1r[7][4];
    #pragma unroll
    for (int mt = 0; mt < 7; ++mt) {
        int f0 = mt*16 + l4*4;
        float4 gv = {0,0,0,0}, bv = {0,0,0,0};
        if (f0 < 100) { gv = *(const float4*)(g1 + f0); bv = *(const float4*)(b1 + f0); }
        #pragma unroll
        for (int r = 0; r < 4; ++r)
            x1r[mt][r] = (f0 < 100) ? (zv[mt][r] - mean) * inv * ((const float*)&gv)[r] + ((const float*)&bv)[r] : 0.f;
    }

    #pragma unroll
    for (int mt = 0; mt < 8; ++mt) {
        float v0 = (mt < 7) ? x1r[mt][0] : 0.f, v1 = (mt < 7) ? x1r[mt][1] : 0.f;
        float v2 = (mt < 7) ? x1r[mt][2] : 0.f, v3 = (mt < 7) ? x1r[mt][3] : 0.f;
        *(uint2v*)(myz + l15*136 + mt*16 + l4*4) = (uint2v){pk2bf(v0, v1), pk2bf(v2, v3)};
    }

    float4v t2[4];
    #pragma unroll
    for (int m2t = 0; m2t < 4; ++m2t) t2[m2t] = (float4v){0,0,0,0};
    #pragma unroll
    for (int ks = 0; ks < 4; ++ks) {
        short8 b = *(const short8*)(myz + l15*136 + ks*32 + l4*8);
        #pragma unroll
        for (int m2t = 0; m2t < 4; ++m2t) {
            short8 a = *(const short8*)((const short*)f1wT + (m2t*16 + l15)*128 + ks*32 + l4*8);
            t2[m2t] = __builtin_amdgcn_mfma_f32_16x16x32_bf16(a, b, t2[m2t], 0, 0, 0);
        }
    }
    #pragma unroll
    for (int m2t = 0; m2t < 4; ++m2t) {
        int m20 = m2t*16 + l4*4;
        float4 bv = *(const float4*)(f1b + m20);
        float v0 = fmaxf(t2[m2t][0] + ((const float*)&bv)[0], 0.f);
        float v1 = fmaxf(t2[m2t][1] + ((const float*)&bv)[1], 0.f);
        float v2 = fmaxf(t2[m2t][2] + ((const float*)&bv)[2], 0.f);
        float v3 = fmaxf(t2[m2t][3] + ((const float*)&bv)[3], 0.f);
        *(uint2v*)(myt + l15*72 + m20) = (uint2v){pk2bf(v0, v1), pk2bf(v2, v3)};
    }

    float4v o3[7];
    #pragma unroll
    for (int m3t = 0; m3t < 7; ++m3t) o3[m3t] = (float4v){0,0,0,0};
    #pragma unroll
    for (int ks2 = 0; ks2 < 2; ++ks2) {
        short8 b = *(const short8*)(myt + l15*72 + ks2*32 + l4*8);
        #pragma unroll
        for (int m3t = 0; m3t < 7; ++m3t) {
            short8 a = *(const short8*)((const short*)f2wT + (m3t*16 + l15)*64 + ks2*32 + l4*8);
            o3[m3t] = __builtin_amdgcn_mfma_f32_16x16x32_bf16(a, b, o3[m3t], 0, 0, 0);
        }
    }

    float z2[7][4];
    float sum2 = 0.f;
    #pragma unroll
    for (int m3t = 0; m3t < 7; ++m3t) {
        int f0 = m3t*16 + l4*4;
        float4 bv = {0,0,0,0};
        if (f0 < 100) bv = *(const float4*)(f2b + f0);
        #pragma unroll
        for (int r = 0; r < 4; ++r) {
            float z = 0.f;
            if (f0 < 100) { z = o3[m3t][r] + ((const float*)&bv)[r] + x1r[m3t][r]; sum2 += z; }
            z2[m3t][r] = z;
        }
    }
    sum2 += __shfl_xor(sum2, 16, 64); sum2 += __shfl_xor(sum2, 32, 64);
    float mean2 = sum2 * 0.01f;
    float vs2 = 0.f;
    #pragma unroll
    for (int m3t = 0; m3t < 7; ++m3t) {
        if (m3t*16 + l4*4 < 100) {
            #pragma unroll
            for (int r = 0; r < 4; ++r) { float d = z2[m3t][r] - mean2; vs2 += d*d; }
        }
    }
    vs2 += __shfl_xor(vs2, 16, 64); vs2 += __shfl_xor(vs2, 32, 64);
    float inv2 = rsqrtf(vs2 * 0.01f + 1e-5f);

    unsigned short* xTc = EMIT ? (xT + (long)cc*98304 + tt) : nullptr;
    #pragma unroll
    for (int m3t = 0; m3t < 7; ++m3t) {
        int f0 = m3t*16 + l4*4;
        if (f0 < 100) {
            float4 gv = *(const float4*)(g2 + f0);
            float4 bv = *(const float4*)(b2 + f0);
            float y[4];
            #pragma unroll
            for (int r = 0; r < 4; ++r)
                y[r] = (z2[m3t][r] - mean2) * inv2 * ((const float*)&gv)[r] + ((const float*)&bv)[r];
            *(float4*)(x + row*100 + f0) = (float4){y[0], y[1], y[2], y[3]};
            if (EMIT) {
                *(uint2v*)(xrow + row*128 + f0) = (uint2v){pk2bf(y[0], y[1]), pk2bf(y[2], y[3])};
                #pragma unroll
                for (int r = 0; r < 4; ++r)
                    xTc[(long)(f0 + r)*768] = f2bf(y[r]);
            }
        } else if (EMIT) {
            *(uint2v*)(xrow + row*128 + f0) = (uint2v){0u, 0u};
            #pragma unroll
            for (int r = 0; r < 4; ++r)
                if (f0 + r < 112) xTc[(long)(f0 + r)*768] = 0;
        }
    }
    if (EMIT) *(uint2v*)(xrow + row*128 + 112 + l4*4) = (uint2v){0u, 0u};
}

// ---------------- autoregressive predictor (composed linear map) ----------------
__global__ void __launch_bounds__(256) k_pred2(const float* __restrict__ xf,
        const float* __restrict__ Mp, const float* __restrict__ c0v,
        float* __restrict__ out) {
    int c = blockIdx.x, tid = threadIdx.x;
    __shared__ float Ml[10000];
    __shared__ float carry[100];
    for (int i = tid; i < 10000; i += 256) Ml[i] = Mp[i];
    if (tid < 100) carry[tid] = xf[((long)c*768 + 767)*100 + tid];
    __syncthreads();
    for (int s = 0; s < 10; ++s) {
        float pv = 0.f;
        if (tid < 100) {
            pv = c0v[tid];
            for (int d = 0; d < 100; ++d) pv += carry[d] * Ml[d*100 + tid];
            out[((long)c*10 + s)*100 + tid] = pv;
        }
        __syncthreads();
        if (tid < 100) carry[tid] = pv;
        __syncthreads();
    }
}

extern "C" void kernel_launch(void* const* d_in, const int* in_sizes, int n_in,
                              void* d_out, int out_size, void* d_ws, size_t ws_size,
                              hipStream_t stream) {
    const float* X    = (const float*)d_in[0];
    const float* A    = (const float*)d_in[1];
    const float* gw1  = (const float*)d_in[2];
    const float* gb1  = (const float*)d_in[3];
    const float* gw2  = (const float*)d_in[4];
    const float* gb2  = (const float*)d_in[5];
    const float* wq   = (const float*)d_in[6];
    const float* wk   = (const float*)d_in[7];
    const float* wv   = (const float*)d_in[8];
    const float* wm   = (const float*)d_in[9];
    const float* f1w  = (const float*)d_in[10];
    const float* f1b  = (const float*)d_in[11];
    const float* f2w  = (const float*)d_in[12];
    const float* f2b  = (const float*)d_in[13];
    const float* ln1g = (const float*)d_in[14];
    const float* ln1b = (const float*)d_in[15];
    const float* ln2g = (const float*)d_in[16];
    const float* ln2b = (const float*)d_in[17];
    const float* l1w  = (const float*)d_in[18];
    const float* l1b  = (const float*)d_in[19];
    const float* l2w  = (const float*)d_in[20];
    const float* l2b  = (const float*)d_in[21];
    (void)in_sizes; (void)n_in; (void)out_size; (void)ws_size;

    float* ws   = (float*)d_ws;
    float* adjh = ws + OFF_ADJ;
    float* x0   = ws + OFF_X0;
    unsigned short* gbuf = (unsigned short*)(ws + OFF_X1);
    unsigned short* hbuf = (unsigned short*)(ws + OFF_X1 + 786432L);
    unsigned short* h2buf= (unsigned short*)(ws + OFF_X1 + 1572864L);
    unsigned short* xrow = (unsigned short*)(ws + OFF_XROW);
    unsigned short* xTb  = (unsigned short*)(ws + OFF_XT);
    unsigned short* Wbf  = (unsigned short*)(ws + OFF_WBF);
    unsigned short* MhT  = (unsigned short*)(ws + OFF_MHT);
    unsigned short* UstT = (unsigned short*)(ws + OFF_USTT);
    float* Mp   = ws + OFF_MP;
    float* c0v  = ws + OFF_C0;
    unsigned short* f1wT = (unsigned short*)(ws + OFF_F1WT);
    unsigned short* f2wT = (unsigned short*)(ws + OFF_F2WT);
    unsigned short* gw1T = (unsigned short*)(ws + OFF_GW1T);
    unsigned short* gw2T = (unsigned short*)(ws + OFF_GW2T);
    float* out  = (float*)d_out;

    k_mu2<<<502, 256, 0, stream>>>(wq, wk, wv, wm, l1w, l1b, l2w, l2b, f1w, f2w, A, gw1, gw2,
                                   MhT, UstT, Mp, c0v, f1wT, f2wT, adjh, gw1T, gw2T);

    // GCN (MFMA weight-gemms; spmms commuted to act on projected tensors)
    k_gw1<<<384, 256, 0, stream>>>(X, gw1T, gbuf);
    k_spmmg<<<192, 256, 0, stream>>>(adjh, gbuf, gb1, hbuf);
    k_gw2<<<384, 256, 0, stream>>>(hbuf, gw2T, h2buf);
    k_spmmx<<<384, 256, 0, stream>>>(adjh, h2buf, gb2, x0);

    // encoder layers: attn + fused tail
    k_prep<<<dim3(12,32), 256, 0, stream>>>(x0, xrow, xTb);
    for (int l = 0; l < 3; ++l) {
        k_attn6<<<dim3(6,5,32), 256, 0, stream>>>(xrow, xTb, MhT + (long)l*81920, Wbf);
        if (l < 2)
            k_tail<true><<<384, 256, 0, stream>>>(Wbf, UstT + (long)l*65536,
                f1wT + (long)l*8192, f2wT + (long)l*7168, f1b + l*64, f2b + l*100,
                ln1g + l*100, ln1b + l*100, ln2g + l*100, ln2b + l*100, x0, xrow, xTb);
        else
            k_tail<false><<<384, 256, 0, stream>>>(Wbf, UstT + (long)l*65536,
                f1wT + (long)l*8192, f2wT + (long)l*7168, f1b + l*64, f2b + l*100,
                ln1g + l*100, ln1b + l*100, ln2g + l*100, ln2b + l*100, x0, xrow, xTb);
    }

    k_pred2<<<32, 256, 0, stream>>>(x0, Mp, c0v, out);
}

// Round 15
// 531.348 us; speedup vs baseline: 1.4402x; 1.0261x over previous
//
#include <hip/hip_runtime.h>

// GTA model: GCN(2-hop) -> 3x transformer encoder -> 10-step AR predictor.
// R14: load-balance pass. k_tail/k_gw1/k_gw2 -> 128-thread blocks (wave-
// private work), 768 blocks = 3/CU balanced (384x256 was 1.5/CU: half the
// CUs ran 2 sequential blocks). k_prep folded into k_spmmx (GCN's last spmm
// emits xrow/xT bf16 directly). Attention = R9 k_attn6 (87us plateau).

#define ROWS 24576   // C*T = 32*768

// workspace offsets (floats)
#define OFF_ADJ   0L
#define OFF_X0    1024L
#define OFF_X1    (OFF_X0 + 2457600L)
#define OFF_XROW  (OFF_X1 + 3932160L)        // 24576*128 bf16 = 1572864 floats
#define OFF_XT    (OFF_XROW + 1572864L)
#define OFF_WBF   (OFF_XT + 1572864L)        // 24576*512 bf16 = 6291456 floats
#define OFF_MHT   (OFF_WBF + 6291456L)       // 15*128*128 bf16 = 122880 floats
#define OFF_USTT  (OFF_MHT + 122880L)        // 3*128*512 bf16 = 98304 floats
#define OFF_MP    (OFF_USTT + 98304L)        // 100*100 fp32
#define OFF_C0    (OFF_MP + 10000L)          // 100 fp32 (pad to 128)
#define OFF_F1WT  (OFF_C0 + 128L)            // 3*64*128 bf16 = 12288 floats
#define OFF_F2WT  (OFF_F1WT + 12288L)        // 3*112*64 bf16 = 10752 floats
#define OFF_GW1T  (OFF_F2WT + 10752L)        // 64*128 bf16 = 4096 floats
#define OFF_GW2T  (OFF_GW1T + 4096L)         // 112*64 bf16 = 3584 floats
// GCN scratch inside OFF_X1 region:
//   g   bf16 24576*64  @ OFF_X1 ; hid bf16 24576*64 @ +786432 ; h2 bf16 24576*128 @ +1572864

typedef __attribute__((ext_vector_type(8))) short short8;
typedef __attribute__((ext_vector_type(4))) float float4v;
typedef __attribute__((ext_vector_type(2))) unsigned int uint2v;

__device__ inline unsigned short f2bf(float f) {
    unsigned u = __builtin_bit_cast(unsigned, f);
    return (unsigned short)((u + 0x7fffu + ((u >> 16) & 1u)) >> 16);
}
__device__ inline unsigned pk2bf(float lo, float hi) {
    return (unsigned)f2bf(lo) | ((unsigned)f2bf(hi) << 16);
}
__device__ inline float bf2f(unsigned short v) {
    return __builtin_bit_cast(float, ((unsigned)v) << 16);
}
// async global->LDS DMA, 16B per lane; LDS dest = wave-uniform base + lane*16
__device__ inline void gload16(const short* g, short* l) {
    __builtin_amdgcn_global_load_lds((const __attribute__((address_space(1))) void*)g,
                                     (__attribute__((address_space(3))) void*)l, 16, 0, 0);
}

// ---------------- precompute: MhT, UstT, f1wT, f2wT, gw1T, gw2T (bf16 padded), Mpred, c0, adjh ----
__global__ void __launch_bounds__(256) k_mu2(const float* __restrict__ wq, const float* __restrict__ wk,
                                             const float* __restrict__ wv, const float* __restrict__ wm,
                                             const float* __restrict__ l1w, const float* __restrict__ l1b,
                                             const float* __restrict__ l2w, const float* __restrict__ l2b,
                                             const float* __restrict__ f1w, const float* __restrict__ f2w,
                                             const float* __restrict__ A,
                                             const float* __restrict__ gw1, const float* __restrict__ gw2,
                                             unsigned short* __restrict__ MhT, unsigned short* __restrict__ UstT,
                                             float* __restrict__ Mp, float* __restrict__ c0v,
                                             unsigned short* __restrict__ f1wT, unsigned short* __restrict__ f2wT,
                                             float* __restrict__ adjh,
                                             unsigned short* __restrict__ gw1T, unsigned short* __restrict__ gw2T) {
    int bi = blockIdx.x, tid = threadIdx.x;
    if (bi < 480) {
        int mat = bi >> 4, sub = bi & 15;
        int mode = mat / 15, idx = mat % 15, l = idx / 5, h = idx % 5;
        const float* Asrc = (mode == 0 ? wq : wv) + (l*5 + h)*10000;
        const float* Bsrc = (mode == 0) ? (wk + (l*5 + h)*10000) : (wm + l*50000 + h*10000);
        int oend = sub*625 + 625;
        for (int o = sub*625 + tid; o < oend; o += 256) {
            int r = o / 100, cix = o - (o/100)*100;
            const float* arow = Asrc + r*100;
            float acc = 0.f;
            if (mode == 0) {
                const float* brow = Bsrc + cix*100;
                for (int e = 0; e < 100; ++e) acc += arow[e] * brow[e];
                MhT[(long)(l*5 + h)*16384 + cix*128 + r] = f2bf(acc * 0.1f);
            } else {
                for (int e = 0; e < 100; ++e) acc += arow[e] * Bsrc[e*100 + cix];
                UstT[(long)l*65536 + (long)cix*512 + h*100 + r] = f2bf(acc);
            }
        }
        if (sub == 0) {   // zero padding
            if (mode == 0) {
                unsigned short* M0 = MhT + (long)(l*5 + h)*16384;
                for (int i = tid; i < 28*128; i += 256) M0[(100 + i/128)*128 + (i%128)] = 0;
                for (int i = tid; i < 100*28; i += 256) M0[(i/28)*128 + 100 + (i%28)] = 0;
            } else if (h == 4) {
                unsigned short* U0 = UstT + (long)l*65536;
                for (int i = tid; i < 28*512; i += 256) U0[(long)(100 + i/512)*512 + (i%512)] = 0;
                for (int i = tid; i < 100*12; i += 256) U0[(long)(i/12)*512 + 500 + (i%12)] = 0;
            }
        }
    } else if (bi < 496) {
        int sub = bi - 480;
        int oend = sub*625 + 625;
        for (int o = sub*625 + tid; o < oend; o += 256) {
            int r = o / 100, cix = o - (o/100)*100;
            const float* arow = l1w + r*200;
            float acc = 0.f;
            for (int e = 0; e < 200; ++e) acc += arow[e] * l2w[e*100 + cix];
            Mp[r*100 + cix] = acc;
        }
    } else if (bi == 496) {
        if (tid < 100) {
            float acc = l2b[tid];
            for (int e = 0; e < 200; ++e) acc += l1b[e] * l2w[e*100 + tid];
            c0v[tid] = acc;
        }
    } else if (bi < 500) {
        int l = bi - 497;   // per-layer FFN weight transposes
        unsigned short* F1 = f1wT + (long)l*8192;
        for (int i = tid; i < 8192; i += 256) {
            int o = i >> 7, k = i & 127;
            F1[i] = (k < 100) ? f2bf(f1w[l*6400 + k*64 + o]) : (unsigned short)0;
        }
        unsigned short* F2 = f2wT + (long)l*7168;
        for (int i = tid; i < 7168; i += 256) {
            int o2 = i >> 6, k2 = i & 63;
            F2[i] = (o2 < 100) ? f2bf(f2w[l*6400 + k2*100 + o2]) : (unsigned short)0;
        }
    } else if (bi == 500) {
        // adjacency normalization
        __shared__ float adj[1024];
        __shared__ float rs[32];
        for (int i = tid; i < 1024; i += 256) {
            int r = i >> 5, j = i & 31;
            adj[i] = A[i] + (r == j ? 1.f : 0.f);
        }
        __syncthreads();
        if (tid < 32) {
            float s = 0.f;
            #pragma unroll
            for (int jj = 0; jj < 32; ++jj) s += adj[tid*32 + jj];
            rs[tid] = s;
        }
        __syncthreads();
        for (int i = tid; i < 1024; i += 256) adjh[i] = adj[i] / rs[i >> 5];
    } else {
        // GCN weight transposes: gw1T[o:64][k:128], gw2T[o:112][k:64]
        for (int i = tid; i < 8192; i += 256) {
            int o = i >> 7, k = i & 127;
            gw1T[i] = (o < 60 && k < 100) ? f2bf(gw1[k*60 + o]) : (unsigned short)0;
        }
        for (int i = tid; i < 7168; i += 256) {
            int o = i >> 6, k = i & 63;
            gw2T[i] = (o < 100 && k < 60) ? f2bf(gw2[k*100 + o]) : (unsigned short)0;
        }
    }
}

// ---------------- GCN gemm1: g[row][64] bf16 = X @ w1 (wave-private MFMA, 32 rows/block) ----
__global__ void __launch_bounds__(128) k_gw1(const float* __restrict__ X,
                                             const unsigned short* __restrict__ gw1T,
                                             unsigned short* __restrict__ g) {
    const int tid = threadIdx.x, wave = tid >> 6, lane = tid & 63;
    const int l15 = lane & 15, l4 = lane >> 4;
    const long row = (long)blockIdx.x*32 + wave*16 + l15;
    const float* xrp = X + row*100;
    float4v acc[4];
    #pragma unroll
    for (int mt = 0; mt < 4; ++mt) acc[mt] = (float4v){0,0,0,0};
    #pragma unroll
    for (int ks = 0; ks < 4; ++ks) {
        short8 b;
        #pragma unroll
        for (int e = 0; e < 8; ++e) {
            int k = ks*32 + l4*8 + e;
            b[e] = (k < 100) ? (short)f2bf(xrp[k]) : (short)0;
        }
        #pragma unroll
        for (int mt = 0; mt < 4; ++mt) {
            short8 a = *(const short8*)((const short*)gw1T + (mt*16 + l15)*128 + ks*32 + l4*8);
            acc[mt] = __builtin_amdgcn_mfma_f32_16x16x32_bf16(a, b, acc[mt], 0, 0, 0);
        }
    }
    #pragma unroll
    for (int mt = 0; mt < 4; ++mt) {
        int o0 = mt*16 + l4*4;
        *(uint2v*)(g + row*64 + o0) =
            (uint2v){pk2bf(acc[mt][0], acc[mt][1]), pk2bf(acc[mt][2], acc[mt][3])};
    }
}

// ---------------- GCN spmm1: hid[row][64] bf16 = relu(adjh @ g + b1) ----------------
__global__ void __launch_bounds__(256) k_spmmg(const float* __restrict__ adjh,
                                               const unsigned short* __restrict__ g,
                                               const float* __restrict__ b1,
                                               unsigned short* __restrict__ hid) {
    __shared__ float adj[1024];
    int tid = threadIdx.x;
    for (int i = tid; i < 1024; i += 256) adj[i] = adjh[i];
    __syncthreads();
    long p = (long)blockIdx.x*256 + tid;     // p = t*64 + o, in [0, 49152)
    int o = (int)(p & 63);
    float acc[32];
    #pragma unroll
    for (int i = 0; i < 32; ++i) acc[i] = 0.f;
    for (int j = 0; j < 32; ++j) {
        float xv = bf2f(g[(long)j*49152 + p]);
        #pragma unroll
        for (int i = 0; i < 32; ++i) acc[i] += adj[i*32 + j] * xv;
    }
    float bias = (o < 60) ? b1[o] : 0.f;
    #pragma unroll
    for (int i = 0; i < 32; ++i) hid[(long)i*49152 + p] = f2bf(fmaxf(acc[i] + bias, 0.f));
}

// ---------------- GCN gemm2: h2[row][128] bf16 = hid @ w2 (32 rows/block) ----------------
__global__ void __launch_bounds__(128) k_gw2(const unsigned short* __restrict__ hid,
                                             const unsigned short* __restrict__ gw2T,
                                             unsigned short* __restrict__ h2) {
    const int tid = threadIdx.x, wave = tid >> 6, lane = tid & 63;
    const int l15 = lane & 15, l4 = lane >> 4;
    const long row = (long)blockIdx.x*32 + wave*16 + l15;
    float4v acc[7];
    #pragma unroll
    for (int mt = 0; mt < 7; ++mt) acc[mt] = (float4v){0,0,0,0};
    #pragma unroll
    for (int ks = 0; ks < 2; ++ks) {
        short8 b = *(const short8*)((const short*)hid + row*64 + ks*32 + l4*8);
        #pragma unroll
        for (int mt = 0; mt < 7; ++mt) {
            short8 a = *(const short8*)((const short*)gw2T + (mt*16 + l15)*64 + ks*32 + l4*8);
            acc[mt] = __builtin_amdgcn_mfma_f32_16x16x32_bf16(a, b, acc[mt], 0, 0, 0);
        }
    }
    #pragma unroll
    for (int mt = 0; mt < 7; ++mt) {
        int o0 = mt*16 + l4*4;
        *(uint2v*)(h2 + row*128 + o0) =
            (uint2v){pk2bf(acc[mt][0], acc[mt][1]), pk2bf(acc[mt][2], acc[mt][3])};
    }
    *(uint2v*)(h2 + row*128 + 112 + l4*4) = (uint2v){0u, 0u};
}

// ---------------- GCN spmm2 + prep: x0 fp32, xrow bf16[row][128], xT bf16[c][128][768] ----
// grid 256 x 384 threads; p = t*128 + o over [0, 98304).
__global__ void __launch_bounds__(384) k_spmmx(const float* __restrict__ adjh,
                                               const unsigned short* __restrict__ h2,
                                               const float* __restrict__ b2,
                                               float* __restrict__ x0,
                                               unsigned short* __restrict__ xrow,
                                               unsigned short* __restrict__ xT) {
    __shared__ float adj[1024];
    int tid = threadIdx.x;
    for (int i = tid; i < 1024; i += 384) adj[i] = adjh[i];
    __syncthreads();
    long p = (long)blockIdx.x*384 + tid;     // p = t*128 + o
    int o = (int)(p & 127);
    int t = (int)(p >> 7);
    float acc[32];
    #pragma unroll
    for (int i = 0; i < 32; ++i) acc[i] = 0.f;
    for (int j = 0; j < 32; ++j) {
        float xv = bf2f(h2[(long)j*98304 + p]);
        #pragma unroll
        for (int i = 0; i < 32; ++i) acc[i] += adj[i*32 + j] * xv;
    }
    if (o < 100) {
        float bias = b2[o];
        #pragma unroll
        for (int i = 0; i < 32; ++i) {
            float v = acc[i] + bias;
            x0[((long)i*768 + t)*100 + o] = v;
            unsigned short bv = f2bf(v);
            xrow[((long)i*768 + t)*128 + o] = bv;
            xT[(long)i*98304 + (long)o*768 + t] = bv;
        }
    } else {
        #pragma unroll
        for (int i = 0; i < 32; ++i) {
            xrow[((long)i*768 + t)*128 + o] = 0;
            if (o < 112) xT[(long)i*98304 + (long)o*768 + t] = 0;
        }
    }
}

// ---------------- fused Q-proj + flash attention, DMA-staged swizzled LDS (R9) ----------------
#define QP_STRIDE 136
#define PT_STRIDE 72

__global__ void __launch_bounds__(256) k_attn6(const unsigned short* __restrict__ xrow,
                                               const unsigned short* __restrict__ xT,
                                               const unsigned short* __restrict__ MhT,
                                               unsigned short* __restrict__ Wb) {
    __shared__ __align__(16) short xr[64 * 128];
    __shared__ __align__(16) short xt[112 * 64];
    __shared__ __align__(16) short scratch[4][2304];
    const int tid = threadIdx.x;
    const int wave = tid >> 6, lane = tid & 63;
    const int l15 = lane & 15, l4 = lane >> 4;
    const int c = blockIdx.z, h = blockIdx.y, q0 = blockIdx.x * 128;
    short* myq = scratch[wave];
    short* pt0 = scratch[wave];
    short* pt1 = scratch[wave] + 1152;

    short8 qb0[4], qb1[4];
    {
        const short* xq = (const short*)xrow + ((long)c*768 + q0 + wave*16 + l15)*128 + l4*8;
        short8 bq0[4], bq1[4];
        #pragma unroll
        for (int kk = 0; kk < 4; ++kk) {
            bq0[kk] = *(const short8*)(xq + kk*32);
            bq1[kk] = *(const short8*)(xq + 64*128 + kk*32);
        }
        const short* Mb = (const short*)MhT + (long)h*16384 + l15*128 + l4*8;
        float4v qc0[8], qc1[8];
        #pragma unroll
        for (int mt = 0; mt < 8; ++mt) { qc0[mt] = (float4v){0,0,0,0}; qc1[mt] = (float4v){0,0,0,0}; }
        #pragma unroll
        for (int mt = 0; mt < 8; ++mt) {
            #pragma unroll
            for (int kk = 0; kk < 4; ++kk) {
                short8 a = *(const short8*)(Mb + (mt*16)*128 + kk*32);
                qc0[mt] = __builtin_amdgcn_mfma_f32_16x16x32_bf16(a, bq0[kk], qc0[mt], 0, 0, 0);
                qc1[mt] = __builtin_amdgcn_mfma_f32_16x16x32_bf16(a, bq1[kk], qc1[mt], 0, 0, 0);
            }
        }
        #pragma unroll
        for (int mt = 0; mt < 8; ++mt)
            *(uint2v*)(myq + l15*QP_STRIDE + mt*16 + l4*4) =
                (uint2v){pk2bf(qc0[mt][0], qc0[mt][1]), pk2bf(qc0[mt][2], qc0[mt][3])};
        #pragma unroll
        for (int kk = 0; kk < 4; ++kk) qb0[kk] = *(const short8*)(myq + l15*QP_STRIDE + kk*32 + l4*8);
        #pragma unroll
        for (int mt = 0; mt < 8; ++mt)
            *(uint2v*)(myq + l15*QP_STRIDE + mt*16 + l4*4) =
                (uint2v){pk2bf(qc1[mt][0], qc1[mt][1]), pk2bf(qc1[mt][2], qc1[mt][3])};
        #pragma unroll
        for (int kk = 0; kk < 4; ++kk) qb1[kk] = *(const short8*)(myq + l15*QP_STRIDE + kk*32 + l4*8);
    }

    float4v o0[7], o1[7];
    #pragma unroll
    for (int n = 0; n < 7; ++n) { o0[n] = (float4v){0,0,0,0}; o1[n] = (float4v){0,0,0,0}; }
    float lsum0 = 0.f, lsum1 = 0.f;

    const short* xrg = (const short*)xrow + (long)c*768*128;
    const short* xtg = (const short*)xT + (long)c*128*768;
    const int rl4 = lane >> 4, cp16 = lane & 15;
    const int rl8 = lane >> 3, cp8 = lane & 7;
    const int njt = (wave == 3) ? 2 : 4;

    for (int kt = 0; kt < 12; ++kt) {
        const int key0 = kt * 64;
        #pragma unroll
        for (int j = 0; j < 4; ++j) {
            int row = wave*16 + j*4 + rl4;
            int lc = cp16 ^ (row & 7);
            gload16(xrg + (long)(key0 + row)*128 + lc*8, xr + (wave*16 + j*4)*128);
        }
        for (int j = 0; j < njt; ++j) {
            int row = wave*32 + j*8 + rl8;
            int lc = cp8 ^ (row & 7);
            gload16(xtg + (long)row*768 + key0 + lc*8, xt + (wave*32 + j*8)*64);
        }
        __syncthreads();

        float4v s0[4], s1[4];
        #pragma unroll
        for (int kn = 0; kn < 4; ++kn) { s0[kn] = (float4v){0,0,0,0}; s1[kn] = (float4v){0,0,0,0}; }
        #pragma unroll
        for (int kn = 0; kn < 4; ++kn) {
            #pragma unroll
            for (int kk = 0; kk < 4; ++kk) {
                short8 a = *(const short8*)(xr + (kn*16 + l15)*128 + (((kk*4 + l4) ^ (l15 & 7))*8));
                s0[kn] = __builtin_amdgcn_mfma_f32_16x16x32_bf16(a, qb0[kk], s0[kn], 0, 0, 0);
                s1[kn] = __builtin_amdgcn_mfma_f32_16x16x32_bf16(a, qb1[kk], s1[kn], 0, 0, 0);
            }
        }

        #pragma unroll
        for (int kn = 0; kn < 4; ++kn) {
            float p0[4], p1[4];
            #pragma unroll
            for (int r = 0; r < 4; ++r) {
                p0[r] = __expf(s0[kn][r]); lsum0 += p0[r];
                p1[r] = __expf(s1[kn][r]); lsum1 += p1[r];
            }
            *(uint2v*)(pt0 + l15*PT_STRIDE + kn*16 + l4*4) =
                (uint2v){pk2bf(p0[0], p0[1]), pk2bf(p0[2], p0[3])};
            *(uint2v*)(pt1 + l15*PT_STRIDE + kn*16 + l4*4) =
                (uint2v){pk2bf(p1[0], p1[1]), pk2bf(p1[2], p1[3])};
        }

        #pragma unroll
        for (int kk2 = 0; kk2 < 2; ++kk2) {
            short8 b0 = *(const short8*)(pt0 + l15*PT_STRIDE + kk2*32 + l4*8);
            short8 b1 = *(const short8*)(pt1 + l15*PT_STRIDE + kk2*32 + l4*8);
            #pragma unroll
            for (int dt = 0; dt < 7; ++dt) {
                short8 a = *(const short8*)(xt + (dt*16 + l15)*64 + (((kk2*4 + l4) ^ (l15 & 7))*8));
                o0[dt] = __builtin_amdgcn_mfma_f32_16x16x32_bf16(a, b0, o0[dt], 0, 0, 0);
                o1[dt] = __builtin_amdgcn_mfma_f32_16x16x32_bf16(a, b1, o1[dt], 0, 0, 0);
            }
        }
        __syncthreads();
    }

    float l0 = lsum0, l1 = lsum1;
    l0 += __shfl_xor(l0, 16, 64); l0 += __shfl_xor(l0, 32, 64);
    l1 += __shfl_xor(l1, 16, 64); l1 += __shfl_xor(l1, 32, 64);
    float inv0 = 1.f / l0, inv1 = 1.f / l1;

    unsigned short* Wo0 = Wb + ((long)(c*768 + q0 + wave*16 + l15))*512 + h*100 + l4*4;
    unsigned short* Wo1 = Wo0 + 64*512;
    #pragma unroll
    for (int dt = 0; dt < 7; ++dt) {
        if (dt < 6 || l4 == 0) {
            *(uint2v*)(Wo0 + dt*16) = (uint2v){pk2bf(o0[dt][0]*inv0, o0[dt][1]*inv0),
                                               pk2bf(o0[dt][2]*inv0, o0[dt][3]*inv0)};
            *(uint2v*)(Wo1 + dt*16) = (uint2v){pk2bf(o1[dt][0]*inv1, o1[dt][1]*inv1),
                                               pk2bf(o1[dt][2]*inv1, o1[dt][3]*inv1)};
        }
    }
    if (h == 0) {
        unsigned short* Wz = Wb + ((long)c*768 + q0)*512 + 500;
        for (int i = tid; i < 1536; i += 256) Wz[(long)(i/12)*512 + (i%12)] = 0;
    }
}

// ---------------- fused encoder tail (32 rows/block, 2 waves): W@Ust+res+LN1+FFN+res+LN2 ----
template<bool EMIT>
__global__ void __launch_bounds__(128) k_tail(const unsigned short* __restrict__ Wb,
        const unsigned short* __restrict__ UstT,
        const unsigned short* __restrict__ f1wT, const unsigned short* __restrict__ f2wT,
        const float* __restrict__ f1b, const float* __restrict__ f2b,
        const float* __restrict__ g1, const float* __restrict__ b1,
        const float* __restrict__ g2, const float* __restrict__ b2,
        float* __restrict__ x, unsigned short* __restrict__ xrow, unsigned short* __restrict__ xT) {
    __shared__ __align__(16) short zS[2][16*136];
    __shared__ __align__(16) short tS[2][16*72];
    const int tid = threadIdx.x, wave = tid >> 6, lane = tid & 63;
    const int l15 = lane & 15, l4 = lane >> 4;
    const long row = (long)blockIdx.x*32 + wave*16 + l15;
    const int cc = blockIdx.x / 24;
    const int tt = (blockIdx.x % 24)*32 + wave*16 + l15;
    short* myz = zS[wave];
    short* myt = tS[wave];

    const short* Wr = (const short*)Wb + row*512 + l4*8;
    float4v o[8];
    #pragma unroll
    for (int mt = 0; mt < 8; ++mt) o[mt] = (float4v){0,0,0,0};
    for (int ks = 0; ks < 16; ++ks) {
        short8 b = *(const short8*)(Wr + ks*32);
        #pragma unroll
        for (int mt = 0; mt < 8; ++mt) {
            short8 a = *(const short8*)((const short*)UstT + (long)(mt*16 + l15)*512 + ks*32 + l4*8);
            o[mt] = __builtin_amdgcn_mfma_f32_16x16x32_bf16(a, b, o[mt], 0, 0, 0);
        }
    }

    float zv[7][4];
    float sum = 0.f;
    #pragma unroll
    for (int mt = 0; mt < 7; ++mt) {
        int f0 = mt*16 + l4*4;
        float4 xv = {0,0,0,0};
        if (f0 < 100) xv = *(const float4*)(x + row*100 + f0);
        #pragma unroll
        for (int r = 0; r < 4; ++r) {
            float z = 0.f;
            if (f0 < 100) { z = o[mt][r] + ((const float*)&xv)[r]; sum += z; }
            zv[mt][r] = z;
        }
    }
    sum += __shfl_xor(sum, 16, 64); sum += __shfl_xor(sum, 32, 64);
    float mean = sum * 0.01f;
    float vs = 0.f;
    #pragma unroll
    for (int mt = 0; mt < 7; ++mt) {
        if (mt*16 + l4*4 < 100) {
            #pragma unroll
            for (int r = 0; r < 4; ++r) { float d = zv[mt][r] - mean; vs += d*d; }
        }
    }
    vs += __shfl_xor(vs, 16, 64); vs += __shfl_xor(vs, 32, 64);
    float inv = rsqrtf(vs * 0.01f + 1e-5f);
    float x1r[7][4];
    #pragma unroll
    for (int mt = 0; mt < 7; ++mt) {
        int f0 = mt*16 + l4*4;
        float4 gv = {0,0,0,0}, bv = {0,0,0,0};
        if (f0 < 100) { gv = *(const float4*)(g1 + f0); bv = *(const float4*)(b1 + f0); }
        #pragma unroll
        for (int r = 0; r < 4; ++r)
            x1r[mt][r] = (f0 < 100) ? (zv[mt][r] - mean) * inv * ((const float*)&gv)[r] + ((const float*)&bv)[r] : 0.f;
    }

    #pragma unroll
    for (int mt = 0; mt < 8; ++mt) {
        float v0 = (mt < 7) ? x1r[mt][0] : 0.f, v1 = (mt < 7) ? x1r[mt][1] : 0.f;
        float v2 = (mt < 7) ? x1r[mt][2] : 0.f, v3 = (mt < 7) ? x1r[mt][3] : 0.f;
        *(uint2v*)(myz + l15*136 + mt*16 + l4*4) = (uint2v){pk2bf(v0, v1), pk2bf(v2, v3)};
    }

    float4v t2[4];
    #pragma unroll
    for (int m2t = 0; m2t < 4; ++m2t) t2[m2t] = (float4v){0,0,0,0};
    #pragma unroll
    for (int ks = 0; ks < 4; ++ks) {
        short8 b = *(const short8*)(myz + l15*136 + ks*32 + l4*8);
        #pragma unroll
        for (int m2t = 0; m2t < 4; ++m2t) {
            short8 a = *(const short8*)((const short*)f1wT + (m2t*16 + l15)*128 + ks*32 + l4*8);
            t2[m2t] = __builtin_amdgcn_mfma_f32_16x16x32_bf16(a, b, t2[m2t], 0, 0, 0);
        }
    }
    #pragma unroll
    for (int m2t = 0; m2t < 4; ++m2t) {
        int m20 = m2t*16 + l4*4;
        float4 bv = *(const float4*)(f1b + m20);
        float v0 = fmaxf(t2[m2t][0] + ((const float*)&bv)[0], 0.f);
        float v1 = fmaxf(t2[m2t][1] + ((const float*)&bv)[1], 0.f);
        float v2 = fmaxf(t2[m2t][2] + ((const float*)&bv)[2], 0.f);
        float v3 = fmaxf(t2[m2t][3] + ((const float*)&bv)[3], 0.f);
        *(uint2v*)(myt + l15*72 + m20) = (uint2v){pk2bf(v0, v1), pk2bf(v2, v3)};
    }

    float4v o3[7];
    #pragma unroll
    for (int m3t = 0; m3t < 7; ++m3t) o3[m3t] = (float4v){0,0,0,0};
    #pragma unroll
    for (int ks2 = 0; ks2 < 2; ++ks2) {
        short8 b = *(const short8*)(myt + l15*72 + ks2*32 + l4*8);
        #pragma unroll
        for (int m3t = 0; m3t < 7; ++m3t) {
            short8 a = *(const short8*)((const short*)f2wT + (m3t*16 + l15)*64 + ks2*32 + l4*8);
            o3[m3t] = __builtin_amdgcn_mfma_f32_16x16x32_bf16(a, b, o3[m3t], 0, 0, 0);
        }
    }

    float z2[7][4];
    float sum2 = 0.f;
    #pragma unroll
    for (int m3t = 0; m3t < 7; ++m3t) {
        int f0 = m3t*16 + l4*4;
        float4 bv = {0,0,0,0};
        if (f0 < 100) bv = *(const float4*)(f2b + f0);
        #pragma unroll
        for (int r = 0; r < 4; ++r) {
            float z = 0.f;
            if (f0 < 100) { z = o3[m3t][r] + ((const float*)&bv)[r] + x1r[m3t][r]; sum2 += z; }
            z2[m3t][r] = z;
        }
    }
    sum2 += __shfl_xor(sum2, 16, 64); sum2 += __shfl_xor(sum2, 32, 64);
    float mean2 = sum2 * 0.01f;
    float vs2 = 0.f;
    #pragma unroll
    for (int m3t = 0; m3t < 7; ++m3t) {
        if (m3t*16 + l4*4 < 100) {
            #pragma unroll
            for (int r = 0; r < 4; ++r) { float d = z2[m3t][r] - mean2; vs2 += d*d; }
        }
    }
    vs2 += __shfl_xor(vs2, 16, 64); vs2 += __shfl_xor(vs2, 32, 64);
    float inv2 = rsqrtf(vs2 * 0.01f + 1e-5f);

    unsigned short* xTc = EMIT ? (xT + (long)cc*98304 + tt) : nullptr;
    #pragma unroll
    for (int m3t = 0; m3t < 7; ++m3t) {
        int f0 = m3t*16 + l4*4;
        if (f0 < 100) {
            float4 gv = *(const float4*)(g2 + f0);
            float4 bv = *(const float4*)(b2 + f0);
            float y[4];
            #pragma unroll
            for (int r = 0; r < 4; ++r)
                y[r] = (z2[m3t][r] - mean2) * inv2 * ((const float*)&gv)[r] + ((const float*)&bv)[r];
            *(float4*)(x + row*100 + f0) = (float4){y[0], y[1], y[2], y[3]};
            if (EMIT) {
                *(uint2v*)(xrow + row*128 + f0) = (uint2v){pk2bf(y[0], y[1]), pk2bf(y[2], y[3])};
                #pragma unroll
                for (int r = 0; r < 4; ++r)
                    xTc[(long)(f0 + r)*768] = f2bf(y[r]);
            }
        } else if (EMIT) {
            *(uint2v*)(xrow + row*128 + f0) = (uint2v){0u, 0u};
            #pragma unroll
            for (int r = 0; r < 4; ++r)
                if (f0 + r < 112) xTc[(long)(f0 + r)*768] = 0;
        }
    }
    if (EMIT) *(uint2v*)(xrow + row*128 + 112 + l4*4) = (uint2v){0u, 0u};
}

// ---------------- autoregressive predictor (composed linear map) ----------------
__global__ void __launch_bounds__(256) k_pred2(const float* __restrict__ xf,
        const float* __restrict__ Mp, const float* __restrict__ c0v,
        float* __restrict__ out) {
    int c = blockIdx.x, tid = threadIdx.x;
    __shared__ float Ml[10000];
    __shared__ float carry[100];
    for (int i = tid; i < 10000; i += 256) Ml[i] = Mp[i];
    if (tid < 100) carry[tid] = xf[((long)c*768 + 767)*100 + tid];
    __syncthreads();
    for (int s = 0; s < 10; ++s) {
        float pv = 0.f;
        if (tid < 100) {
            pv = c0v[tid];
            for (int d = 0; d < 100; ++d) pv += carry[d] * Ml[d*100 + tid];
            out[((long)c*10 + s)*100 + tid] = pv;
        }
        __syncthreads();
        if (tid < 100) carry[tid] = pv;
        __syncthreads();
    }
}

extern "C" void kernel_launch(void* const* d_in, const int* in_sizes, int n_in,
                              void* d_out, int out_size, void* d_ws, size_t ws_size,
                              hipStream_t stream) {
    const float* X    = (const float*)d_in[0];
    const float* A    = (const float*)d_in[1];
    const float* gw1  = (const float*)d_in[2];
    const float* gb1  = (const float*)d_in[3];
    const float* gw2  = (const float*)d_in[4];
    const float* gb2  = (const float*)d_in[5];
    const float* wq   = (const float*)d_in[6];
    const float* wk   = (const float*)d_in[7];
    const float* wv   = (const float*)d_in[8];
    const float* wm   = (const float*)d_in[9];
    const float* f1w  = (const float*)d_in[10];
    const float* f1b  = (const float*)d_in[11];
    const float* f2w  = (const float*)d_in[12];
    const float* f2b  = (const float*)d_in[13];
    const float* ln1g = (const float*)d_in[14];
    const float* ln1b = (const float*)d_in[15];
    const float* ln2g = (const float*)d_in[16];
    const float* ln2b = (const float*)d_in[17];
    const float* l1w  = (const float*)d_in[18];
    const float* l1b  = (const float*)d_in[19];
    const float* l2w  = (const float*)d_in[20];
    const float* l2b  = (const float*)d_in[21];
    (void)in_sizes; (void)n_in; (void)out_size; (void)ws_size;

    float* ws   = (float*)d_ws;
    float* adjh = ws + OFF_ADJ;
    float* x0   = ws + OFF_X0;
    unsigned short* gbuf = (unsigned short*)(ws + OFF_X1);
    unsigned short* hbuf = (unsigned short*)(ws + OFF_X1 + 786432L);
    unsigned short* h2buf= (unsigned short*)(ws + OFF_X1 + 1572864L);
    unsigned short* xrow = (unsigned short*)(ws + OFF_XROW);
    unsigned short* xTb  = (unsigned short*)(ws + OFF_XT);
    unsigned short* Wbf  = (unsigned short*)(ws + OFF_WBF);
    unsigned short* MhT  = (unsigned short*)(ws + OFF_MHT);
    unsigned short* UstT = (unsigned short*)(ws + OFF_USTT);
    float* Mp   = ws + OFF_MP;
    float* c0v  = ws + OFF_C0;
    unsigned short* f1wT = (unsigned short*)(ws + OFF_F1WT);
    unsigned short* f2wT = (unsigned short*)(ws + OFF_F2WT);
    unsigned short* gw1T = (unsigned short*)(ws + OFF_GW1T);
    unsigned short* gw2T = (unsigned short*)(ws + OFF_GW2T);
    float* out  = (float*)d_out;

    k_mu2<<<502, 256, 0, stream>>>(wq, wk, wv, wm, l1w, l1b, l2w, l2b, f1w, f2w, A, gw1, gw2,
                                   MhT, UstT, Mp, c0v, f1wT, f2wT, adjh, gw1T, gw2T);

    // GCN (MFMA weight-gemms; spmms commuted; last spmm emits xrow/xT directly)
    k_gw1<<<768, 128, 0, stream>>>(X, gw1T, gbuf);
    k_spmmg<<<192, 256, 0, stream>>>(adjh, gbuf, gb1, hbuf);
    k_gw2<<<768, 128, 0, stream>>>(hbuf, gw2T, h2buf);
    k_spmmx<<<256, 384, 0, stream>>>(adjh, h2buf, gb2, x0, xrow, xTb);

    // encoder layers: attn + fused tail
    for (int l = 0; l < 3; ++l) {
        k_attn6<<<dim3(6,5,32), 256, 0, stream>>>(xrow, xTb, MhT + (long)l*81920, Wbf);
        if (l < 2)
            k_tail<true><<<768, 128, 0, stream>>>(Wbf, UstT + (long)l*65536,
                f1wT + (long)l*8192, f2wT + (long)l*7168, f1b + l*64, f2b + l*100,
                ln1g + l*100, ln1b + l*100, ln2g + l*100, ln2b + l*100, x0, xrow, xTb);
        else
            k_tail<false><<<768, 128, 0, stream>>>(Wbf, UstT + (long)l*65536,
                f1wT + (long)l*8192, f2wT + (long)l*7168, f1b + l*64, f2b + l*100,
                ln1g + l*100, ln1b + l*100, ln2g + l*100, ln2b + l*100, x0, xrow, xTb);
    }

    k_pred2<<<32, 256, 0, stream>>>(x0, Mp, c0v, out);
}